// Round 15
// baseline (242.962 us; speedup 1.0000x reference)
//
#include <hip/hip_runtime.h>
#include <hip/hip_bf16.h>
#include <stdint.h>

#define NB 16
#define CDIM 96
#define HW 112
#define NPOS (HW*HW)      // 12544
#define NHEAD 3
#define DH 32
#define WN 16
#define NWIN (WN*WN)
#define SCALE 0.17677669529663687f

typedef __attribute__((ext_vector_type(8))) short bf16x8;
typedef __attribute__((ext_vector_type(4))) float f32x4;

// ---------- bf16 helpers ----------
__device__ __forceinline__ float bfbits_lo(uint32_t w){ union{uint32_t u; float f;} a; a.u = w<<16; return a.f; }
__device__ __forceinline__ float bfbits_hi(uint32_t w){ union{uint32_t u; float f;} a; a.u = w & 0xFFFF0000u; return a.f; }
__device__ __forceinline__ uint32_t packbf(float x, float y){
  union{float f; uint32_t u;} a, b; a.f = x; b.f = y;
  uint32_t ua = a.u + 0x7FFFu + ((a.u>>16)&1u);
  uint32_t ub = b.u + 0x7FFFu + ((b.u>>16)&1u);
  return (ua>>16) | (ub & 0xFFFF0000u);
}
__device__ __forceinline__ unsigned short f2bf(float x){
  union{float f; uint32_t u;} a; a.f = x;
  return (unsigned short)((a.u + 0x7FFFu + ((a.u>>16)&1u))>>16);
}

// ---------- K0: weights -> bf16 in global (L2-resident, read as fragments) ----------
__global__ void k_wpre(const float* __restrict__ wqkv, const float* __restrict__ wproj,
                       unsigned short* __restrict__ w16q, unsigned short* __restrict__ w16p){
  int n = blockIdx.x*256 + threadIdx.x;
  if (n < 288*96) w16q[n] = f2bf(wqkv[n]);
  if (n < 96*96)  w16p[n] = f2bf(wproj[n]);
}

// ---------- K1: 7x7 mean pool + leaky relu ----------
__global__ void k_pool_act(const float* __restrict__ x, float* __restrict__ act){
  int n = blockIdx.x*256 + threadIdx.x;
  int ww = n & 15; int wh = (n>>4)&15; int bc = n>>8;
  const float* src = x + (size_t)bc*NPOS + (size_t)(wh*7)*HW + ww*7;
  float s = 0.f;
  #pragma unroll
  for (int r=0;r<7;r++){
    const float* row = src + r*HW;
    s += row[0]+row[1]+row[2]+row[3]+row[4]+row[5]+row[6];
  }
  s *= (1.f/49.f);
  act[n] = s > 0.f ? s : 0.01f*s;
}

// ---------- K2: offsets / scales per window ----------
__global__ void k_offscl(const float* __restrict__ act,
                         const float* __restrict__ woff, const float* __restrict__ boff,
                         const float* __restrict__ wscl, const float* __restrict__ bscl,
                         float4* __restrict__ offscl){
  int n = blockIdx.x*256 + threadIdx.x;
  int b = n >> 8; int wpos = n & 255;
  float accO[6], accS[6];
  #pragma unroll
  for (int o=0;o<6;o++){ accO[o]=boff[o]; accS[o]=bscl[o]; }
  const float* a = act + (size_t)b*CDIM*NWIN + wpos;
  for (int c=0;c<CDIM;c++){
    float av = a[(size_t)c*NWIN];
    #pragma unroll
    for (int o=0;o<6;o++){ accO[o] += av*woff[o*CDIM+c]; accS[o] += av*wscl[o*CDIM+c]; }
  }
  #pragma unroll
  for (int h=0;h<NHEAD;h++){
    float4 r;
    r.x = accO[2*h]   * (1.f/16.f);
    r.y = accO[2*h+1] * (1.f/16.f);
    r.z = accS[2*h];
    r.w = accS[2*h+1];
    offscl[(size_t)(b*NHEAD+h)*NWIN + wpos] = r;
  }
}

// ---------- K2b: padded bias table [3][64 q][64 k]; k>=49 -> -1e30 ----------
__global__ void k_bias_pre(const float* __restrict__ rpb, float* __restrict__ bias_g){
  int n = blockIdx.x*256 + threadIdx.x;
  if (n >= 3*64*64) return;
  int h = n >> 12; int q = (n>>6)&63; int k = n&63;
  float v = -1e30f;
  if (k < 49){
    int qc = q < 49 ? q : 48;
    int qi = qc/7, qj = qc - (qc/7)*7;
    int ki = k/7,  kj = k - (k/7)*7;
    v = rpb[((qi-ki+6)*13 + (qj-kj+6))*3 + h];
  }
  bias_g[n] = v;
}

// ---------- K3: qkv projection via bf16 MFMA, ZERO LDS ----------
// A-frags by direct strided register loads (lane reads its 8 channels at its
// own pos; wave = 4x64B segments/inst, coalesced). W-frags direct from the
// precomputed bf16 table (L2-hot). No barriers, no staging phases.
__launch_bounds__(256)
__global__ void k_qkv_mfma(const float* __restrict__ x, const unsigned short* __restrict__ w16,
                           const float* __restrict__ bqkv,
                           unsigned short* __restrict__ q, unsigned short* __restrict__ kk,
                           unsigned short* __restrict__ v){
  const int t = threadIdx.x;
  const int b = blockIdx.x / 196;
  const int p0 = (blockIdx.x % 196) * 64;
  const int lane = t & 63, wv = t >> 6;
  const int g = lane >> 4, r16 = lane & 15;
  const int pos = p0 + wv*16 + r16;

  // A-fragments: af[ks] = channels ks*32+8g .. +7 at pos (bit-identical to
  // the old LDS-transpose product).
  uint4 afu[3];
  {
    const float* xb = x + (size_t)b*CDIM*NPOS + pos;
    #pragma unroll
    for (int ks=0;ks<3;ks++){
      float xv[8];
      #pragma unroll
      for (int j=0;j<8;j++) xv[j] = xb[(size_t)(ks*32 + 8*g + j)*NPOS];
      afu[ks] = make_uint4(packbf(xv[0],xv[1]), packbf(xv[2],xv[3]),
                           packbf(xv[4],xv[5]), packbf(xv[6],xv[7]));
    }
  }

  for (int s=0;s<3;s++){
    f32x4 acc[6];
    #pragma unroll
    for (int nf=0;nf<6;nf++) acc[nf] = (f32x4){0.f,0.f,0.f,0.f};
    #pragma unroll
    for (int ks=0;ks<3;ks++){
      #pragma unroll
      for (int nf=0;nf<6;nf++){
        uint4 wu = *(const uint4*)(w16 + ((size_t)(s*96 + nf*16 + r16)*96 + ks*32 + 8*g));
        acc[nf] = __builtin_amdgcn_mfma_f32_16x16x32_bf16(*(const bf16x8*)&wu,
                                                          *(const bf16x8*)&afu[ks], acc[nf], 0,0,0);
      }
    }
    unsigned short* dst = (s==0)?q:((s==1)?kk:v);
    float sc = (s==0) ? SCALE : 1.f;
    #pragma unroll
    for (int nf=0;nf<6;nf++){
      int o0 = nf*16 + 4*g;
      int hh = o0 >> 5; int d0 = o0 & 31;
      float4 bv = *(const float4*)(bqkv + s*96 + o0);
      uint2 pk = make_uint2(packbf((acc[nf][0]+bv.x)*sc, (acc[nf][1]+bv.y)*sc),
                            packbf((acc[nf][2]+bv.z)*sc, (acc[nf][3]+bv.w)*sc));
      *(uint2*)(dst + ((size_t)(b*NHEAD+hh)*NPOS + pos)*DH + d0) = pk;
    }
  }
}

// ---------- K4 v3b: fused bilinear sample + window attention ----------
// FROZEN byte-identical to round 11/13 (passing). Six schedule perturbations
// (R6,7,8,10,12,14) each broke it with ~1e-3 error. Do not touch.
__launch_bounds__(128)
__global__ void k_attn_mfma(const unsigned short* __restrict__ qb,
                            const unsigned short* __restrict__ kb,
                            const unsigned short* __restrict__ vb,
                            const float4* __restrict__ offscl,
                            const float* __restrict__ bias_g,
                            float* __restrict__ aout){
  __shared__ unsigned short VT_all[2*2048];  // 8 KB: [wave][32 dh][64 pos] swizzled
  const int h   = blockIdx.x % 3;
  const int grp = blockIdx.x / 3;
  const int wv  = threadIdx.x >> 6;
  const int lane = threadIdx.x & 63;
  const int win = grp*2 + wv;
  const int b = win>>8, wh=(win>>4)&15, ww=win&15;
  const int bh = b*NHEAD + h;
  const int g = lane>>4, r16 = lane&15;
  unsigned short* VT_s = VT_all + wv*2048;

  // ---- Q fragments (B operand of S^T: col=q, k=ch) ----
  uint4 qf[4];
  #pragma unroll
  for (int qt=0;qt<4;qt++){
    int qq = qt*16 + r16; if (qq > 48) qq = 48;
    int qi = qq/7; int qj = qq - qi*7;
    size_t pos = (size_t)(wh*7+qi)*HW + ww*7 + qj;
    qf[qt] = *(const uint4*)(qb + ((size_t)bh*NPOS + pos)*DH + g*8);
  }

  // ---- phase 1: per-lane sample coords for kv pos = lane ----
  int ki = lane/7; int kj = lane - ki*7;
  uint32_t nbaddr[4]; float nbw[4];
  {
    float4 os = offscl[(size_t)bh*NWIN + (wh*16+ww)];
    float px = (float)(ww*7+kj) + (float)(kj-3)*os.z + 55.5f*os.x;
    float py = (float)(wh*7+ki) + (float)(ki-3)*os.w + 55.5f*os.y;
    float x0f = floorf(px), y0f = floorf(py);
    float fx = px-x0f, fy = py-y0f;
    int x0 = (int)x0f, y0 = (int)y0f;
    float wb[4] = {(1.f-fx)*(1.f-fy), fx*(1.f-fy), (1.f-fx)*fy, fx*fy};
    bool qok = lane < 49;
    #pragma unroll
    for (int nb=0;nb<4;nb++){
      int xi = x0 + (nb&1), yi = y0 + (nb>>1);
      int xc = min(max(xi,0),HW-1), yc = min(max(yi,0),HW-1);
      nbaddr[nb] = (uint32_t)(yc*HW + xc) * 64u;   // byte offset (64B rows)
      nbw[nb] = (qok && xi==xc && yi==yc) ? wb[nb] : 0.f;
    }
  }

  // ---- phase 2: team gather; K stays in registers, V -> VT_s ----
  const char* kb8 = (const char*)kb + (size_t)bh*NPOS*64;
  const char* vb8 = (const char*)vb + (size_t)bh*NPOS*64;
  uint4 kfrag[4];
  #pragma unroll
  for (int pp=0;pp<4;pp++){
    int spos = pp*16 + r16;                        // kv row this 4-lane team handles
    float ka[8], va[8];
    #pragma unroll
    for (int j=0;j<8;j++){ ka[j]=0.f; va[j]=0.f; }
    #pragma unroll
    for (int nb=0;nb<4;nb++){
      uint32_t a = (uint32_t)__shfl((int)nbaddr[nb], spos);
      float    w = __shfl(nbw[nb], spos);
      uint4 uk = *(const uint4*)(kb8 + a + g*16);
      uint4 uv = *(const uint4*)(vb8 + a + g*16);
      ka[0]+=w*bfbits_lo(uk.x); ka[1]+=w*bfbits_hi(uk.x);
      ka[2]+=w*bfbits_lo(uk.y); ka[3]+=w*bfbits_hi(uk.y);
      ka[4]+=w*bfbits_lo(uk.z); ka[5]+=w*bfbits_hi(uk.z);
      ka[6]+=w*bfbits_lo(uk.w); ka[7]+=w*bfbits_hi(uk.w);
      va[0]+=w*bfbits_lo(uv.x); va[1]+=w*bfbits_hi(uv.x);
      va[2]+=w*bfbits_lo(uv.y); va[3]+=w*bfbits_hi(uv.y);
      va[4]+=w*bfbits_lo(uv.z); va[5]+=w*bfbits_hi(uv.z);
      va[6]+=w*bfbits_lo(uv.w); va[7]+=w*bfbits_hi(uv.w);
    }
    // K A-fragment for at=pp: lane(r16,g) holds K[pp*16+r16][8g..8g+7]
    kfrag[pp] = make_uint4(packbf(ka[0],ka[1]), packbf(ka[2],ka[3]),
                           packbf(ka[4],ka[5]), packbf(ka[6],ka[7]));
    // VT_s: row d, slot = (pos>>3) ^ (d&7), elem = pos&7 (round-5 proven layout)
    #pragma unroll
    for (int j=0;j<8;j++){
      int d = g*8 + j;
      VT_s[d*64 + (((spos>>3) ^ (d&7))*8) + (spos&7)] = f2bf(va[j]);
    }
  }

  // Real barrier (2 waves): orders VT_s short-writes before bf16x8 reads
  // across the TBAA gap. sched_barrier as compiler-level insurance.
  __builtin_amdgcn_sched_barrier(0);
  __syncthreads();
  __builtin_amdgcn_sched_barrier(0);

  // ---- S^T = K * Q^T + bias ----
  const float* bias_h = bias_g + h*4096;
  f32x4 acc[4][4];                               // [at = k-tile][qt]
  #pragma unroll
  for (int qt=0;qt<4;qt++){
    int qq = qt*16 + r16;
    #pragma unroll
    for (int at=0;at<4;at++)
      acc[at][qt] = *(const f32x4*)(bias_h + qq*64 + at*16 + g*4);
  }
  #pragma unroll
  for (int at=0;at<4;at++){
    bf16x8 a = *(const bf16x8*)&kfrag[at];
    #pragma unroll
    for (int qt=0;qt<4;qt++)
      acc[at][qt] = __builtin_amdgcn_mfma_f32_16x16x32_bf16(a, *(const bf16x8*)&qf[qt], acc[at][qt], 0,0,0);
  }

  // ---- softmax over k (rows of S^T): in-lane 16 + 2 shfl ----
  #pragma unroll
  for (int qt=0;qt<4;qt++){
    float m = acc[0][qt][0];
    #pragma unroll
    for (int at=0;at<4;at++)
      #pragma unroll
      for (int rr=0;rr<4;rr++) m = fmaxf(m, acc[at][qt][rr]);
    m = fmaxf(m, __shfl_xor(m, 16));
    m = fmaxf(m, __shfl_xor(m, 32));
    float s = 0.f;
    #pragma unroll
    for (int at=0;at<4;at++)
      #pragma unroll
      for (int rr=0;rr<4;rr++){ float e = __expf(acc[at][qt][rr]-m); acc[at][qt][rr]=e; s+=e; }
    s += __shfl_xor(s, 16);
    s += __shfl_xor(s, 32);
    float rl = 1.f/s;
    #pragma unroll
    for (int at=0;at<4;at++)
      #pragma unroll
      for (int rr=0;rr<4;rr++) acc[at][qt][rr] *= rl;
  }

  // ---- pack P to bf16 pairs: lane(g_src,r16) holds k = at*16 + 4*g_src + rr ----
  uint32_t plo[4][4], phi[4][4];                 // [at][qt]
  #pragma unroll
  for (int at=0;at<4;at++)
    #pragma unroll
    for (int qt=0;qt<4;qt++){
      plo[at][qt] = packbf(acc[at][qt][0], acc[at][qt][1]);
      phi[at][qt] = packbf(acc[at][qt][2], acc[at][qt][3]);
    }

  // ---- O^T = V^T * P^T : A = V^T rows (VT_s), B = P^T via in-register shfl ----
  // B-frag (qt,kt): lane(r16,g) needs P[qt*16+r16][k = kt*32 + 8g + j], j=0..7.
  // Source: at = 2kt + (g>>1), g_src = (2g + (j>>2))&3.
  f32x4 o[2][4];                                 // [dt = d-tile][qt]
  #pragma unroll
  for (int dt=0;dt<2;dt++)
    #pragma unroll
    for (int qt=0;qt<4;qt++) o[dt][qt] = (f32x4){0.f,0.f,0.f,0.f};

  #pragma unroll
  for (int kt=0;kt<2;kt++){
    uint4 pfrag[4];
    const int s0 = ((2*g)&3)*16 + r16;
    const int s1 = ((2*g+1)&3)*16 + r16;
    const bool odd = (g & 2);
    #pragma unroll
    for (int qt=0;qt<4;qt++){
      uint32_t e_lo0 = (uint32_t)__shfl((int)plo[2*kt  ][qt], s0);
      uint32_t e_hi0 = (uint32_t)__shfl((int)phi[2*kt  ][qt], s0);
      uint32_t e_lo1 = (uint32_t)__shfl((int)plo[2*kt  ][qt], s1);
      uint32_t e_hi1 = (uint32_t)__shfl((int)phi[2*kt  ][qt], s1);
      uint32_t o_lo0 = (uint32_t)__shfl((int)plo[2*kt+1][qt], s0);
      uint32_t o_hi0 = (uint32_t)__shfl((int)phi[2*kt+1][qt], s0);
      uint32_t o_lo1 = (uint32_t)__shfl((int)plo[2*kt+1][qt], s1);
      uint32_t o_hi1 = (uint32_t)__shfl((int)phi[2*kt+1][qt], s1);
      pfrag[qt] = make_uint4(odd?o_lo0:e_lo0, odd?o_hi0:e_hi0,
                             odd?o_lo1:e_lo1, odd?o_hi1:e_hi1);
    }
    #pragma unroll
    for (int dt=0;dt<2;dt++){
      int d = dt*16 + r16;
      bf16x8 a = *(const bf16x8*)&VT_s[d*64 + (((kt*4+g) ^ (d&7))*8)];
      #pragma unroll
      for (int qt=0;qt<4;qt++)
        o[dt][qt] = __builtin_amdgcn_mfma_f32_16x16x32_bf16(a, *(const bf16x8*)&pfrag[qt], o[dt][qt], 0,0,0);
    }
  }

  // ---- store O^T: lane-col = q (few lines per instruction) ----
  float* outb = aout + ((size_t)b*CDIM + h*DH)*NPOS;
  #pragma unroll
  for (int qt=0;qt<4;qt++){
    int q = qt*16 + r16;
    if (q < 49){
      int qi = q/7; int qj = q - qi*7;
      size_t opix = (size_t)(wh*7+qi)*HW + ww*7 + qj;
      #pragma unroll
      for (int dt=0;dt<2;dt++)
        #pragma unroll
        for (int rr=0;rr<4;rr++){
          int d = dt*16 + g*4 + rr;
          outb[(size_t)d*NPOS + opix] = o[dt][qt][rr];
        }
    }
  }
}

// ---------- K5: output projection via bf16 MFMA, ZERO LDS, IN PLACE ----------
// In-place safety: all of this block's input reads complete (fence drains
// vmcnt before s_barrier) before any store; blocks touch disjoint slices.
__launch_bounds__(256)
__global__ void k_proj_mfma(const float* yin, const unsigned short* __restrict__ w16,
                            const float* __restrict__ bproj, float* yout){
  const int t = threadIdx.x;
  const int b = blockIdx.x / 196;
  const int p0 = (blockIdx.x % 196) * 64;
  const int lane = t & 63, wv = t >> 6;
  const int g = lane >> 4, r16 = lane & 15;
  const int pos = p0 + wv*16 + r16;

  uint4 afu[3];
  {
    const float* xb = yin + (size_t)b*CDIM*NPOS + pos;
    #pragma unroll
    for (int ks=0;ks<3;ks++){
      float xv[8];
      #pragma unroll
      for (int j=0;j<8;j++) xv[j] = xb[(size_t)(ks*32 + 8*g + j)*NPOS];
      afu[ks] = make_uint4(packbf(xv[0],xv[1]), packbf(xv[2],xv[3]),
                           packbf(xv[4],xv[5]), packbf(xv[6],xv[7]));
    }
  }

  f32x4 acc[6];
  #pragma unroll
  for (int nf=0;nf<6;nf++) acc[nf] = (f32x4){0.f,0.f,0.f,0.f};
  #pragma unroll
  for (int ks=0;ks<3;ks++){
    #pragma unroll
    for (int nf=0;nf<6;nf++){
      uint4 wu = *(const uint4*)(w16 + ((size_t)(nf*16 + r16)*96 + ks*32 + 8*g));
      acc[nf] = __builtin_amdgcn_mfma_f32_16x16x32_bf16(*(const bf16x8*)&wu,
                                                        *(const bf16x8*)&afu[ks], acc[nf], 0,0,0);
    }
  }

  // Barrier: all block-slice reads done before in-place writes begin.
  __syncthreads();

  #pragma unroll
  for (int nf=0;nf<6;nf++){
    int o0 = nf*16 + 4*g;
    float4 bv = *(const float4*)(bproj + o0);
    yout[(size_t)(b*CDIM+o0+0)*NPOS + pos] = acc[nf][0] + bv.x;
    yout[(size_t)(b*CDIM+o0+1)*NPOS + pos] = acc[nf][1] + bv.y;
    yout[(size_t)(b*CDIM+o0+2)*NPOS + pos] = acc[nf][2] + bv.z;
    yout[(size_t)(b*CDIM+o0+3)*NPOS + pos] = acc[nf][3] + bv.w;
  }
}

extern "C" void kernel_launch(void* const* d_in, const int* in_sizes, int n_in,
                              void* d_out, int out_size, void* d_ws, size_t ws_size,
                              hipStream_t stream) {
  const float* x      = (const float*)d_in[0];
  const float* w_qkv  = (const float*)d_in[1];
  const float* b_qkv  = (const float*)d_in[2];
  const float* w_off  = (const float*)d_in[3];
  const float* b_off  = (const float*)d_in[4];
  const float* w_scl  = (const float*)d_in[5];
  const float* b_scl  = (const float*)d_in[6];
  const float* rpb    = (const float*)d_in[7];
  const float* w_proj = (const float*)d_in[8];
  const float* b_proj = (const float*)d_in[9];

  char* ws = (char*)d_ws;
  float*   act    = (float*)(ws + 0);                  // 1,572,864 B
  float4*  offscl = (float4*)(ws + 1572864);           //   196,608 B
  float*   bias_g = (float*)(ws + 1769472);            //    49,152 B
  unsigned short* w16q = (unsigned short*)(ws + 1818624); // 55,296 B
  unsigned short* w16p = (unsigned short*)(ws + 1873920); // 18,432 B
  const size_t QKV_BYTES = (size_t)NB*NHEAD*NPOS*DH*2; // 38,535,168 B each
  unsigned short* qbuf = (unsigned short*)(ws + 2097152);
  unsigned short* kbuf = (unsigned short*)(ws + 2097152 + QKV_BYTES);
  unsigned short* vbuf = (unsigned short*)(ws + 2097152 + 2*QKV_BYTES);

  hipLaunchKernelGGL(k_wpre,      dim3(108),  dim3(256), 0, stream, w_qkv, w_proj, w16q, w16p);
  hipLaunchKernelGGL(k_pool_act,  dim3(1536), dim3(256), 0, stream, x, act);
  hipLaunchKernelGGL(k_offscl,    dim3(16),   dim3(256), 0, stream, act, w_off, b_off, w_scl, b_scl, offscl);
  hipLaunchKernelGGL(k_bias_pre,  dim3(48),   dim3(256), 0, stream, rpb, bias_g);
  hipLaunchKernelGGL(k_qkv_mfma,  dim3(16*196), dim3(256), 0, stream, x, w16q, b_qkv, qbuf, kbuf, vbuf);
  hipLaunchKernelGGL(k_attn_mfma, dim3(3*2048), dim3(128), 0, stream,
                     qbuf, kbuf, vbuf, offscl, bias_g, (float*)d_out);
  hipLaunchKernelGGL(k_proj_mfma, dim3(16*196), dim3(256), 0, stream,
                     (const float*)d_out, w16p, b_proj, (float*)d_out);
}

// Round 16
// 239.353 us; speedup vs baseline: 1.0151x; 1.0151x over previous
//
#include <hip/hip_runtime.h>
#include <hip/hip_bf16.h>
#include <stdint.h>

#define NB 16
#define CDIM 96
#define HW 112
#define NPOS (HW*HW)      // 12544
#define NHEAD 3
#define DH 32
#define WN 16
#define NWIN (WN*WN)
#define SCALE 0.17677669529663687f

typedef __attribute__((ext_vector_type(8))) short bf16x8;
typedef __attribute__((ext_vector_type(4))) float f32x4;

// ---------- bf16 helpers ----------
__device__ __forceinline__ float bfbits_lo(uint32_t w){ union{uint32_t u; float f;} a; a.u = w<<16; return a.f; }
__device__ __forceinline__ float bfbits_hi(uint32_t w){ union{uint32_t u; float f;} a; a.u = w & 0xFFFF0000u; return a.f; }
__device__ __forceinline__ uint32_t packbf(float x, float y){
  union{float f; uint32_t u;} a, b; a.f = x; b.f = y;
  uint32_t ua = a.u + 0x7FFFu + ((a.u>>16)&1u);
  uint32_t ub = b.u + 0x7FFFu + ((b.u>>16)&1u);
  return (ua>>16) | (ub & 0xFFFF0000u);
}
__device__ __forceinline__ unsigned short f2bf(float x){
  union{float f; uint32_t u;} a; a.f = x;
  return (unsigned short)((a.u + 0x7FFFu + ((a.u>>16)&1u))>>16);
}

// ---------- K0: bias table + weight bf16 conversion (fused small pre-pass) ----------
__global__ void k_pre(const float* __restrict__ rpb, float* __restrict__ bias_g,
                      const float* __restrict__ wqkv, const float* __restrict__ wproj,
                      unsigned short* __restrict__ w16q, unsigned short* __restrict__ w16p){
  int n = blockIdx.x*256 + threadIdx.x;          // grid 108*256 = 27,648
  if (n < 288*96) w16q[n] = f2bf(wqkv[n]);
  if (n < 96*96)  w16p[n] = f2bf(wproj[n]);
  if (n < 3*64*64){
    int h = n >> 12; int q = (n>>6)&63; int k = n&63;
    float v = -1e30f;
    if (k < 49){
      int qc = q < 49 ? q : 48;
      int qi = qc/7, qj = qc - (qc/7)*7;
      int ki = k/7,  kj = k - (k/7)*7;
      v = rpb[((qi-ki+6)*13 + (qj-kj+6))*3 + h];
    }
    bias_g[n] = v;
  }
}

// ---------- K1: 7x7 mean pool + leaky relu ----------
__global__ void k_pool_act(const float* __restrict__ x, float* __restrict__ act){
  int n = blockIdx.x*256 + threadIdx.x;
  int ww = n & 15; int wh = (n>>4)&15; int bc = n>>8;
  const float* src = x + (size_t)bc*NPOS + (size_t)(wh*7)*HW + ww*7;
  float s = 0.f;
  #pragma unroll
  for (int r=0;r<7;r++){
    const float* row = src + r*HW;
    s += row[0]+row[1]+row[2]+row[3]+row[4]+row[5]+row[6];
  }
  s *= (1.f/49.f);
  act[n] = s > 0.f ? s : 0.01f*s;
}

// ---------- K2: offsets / scales per window ----------
__global__ void k_offscl(const float* __restrict__ act,
                         const float* __restrict__ woff, const float* __restrict__ boff,
                         const float* __restrict__ wscl, const float* __restrict__ bscl,
                         float4* __restrict__ offscl){
  int n = blockIdx.x*256 + threadIdx.x;
  int b = n >> 8; int wpos = n & 255;
  float accO[6], accS[6];
  #pragma unroll
  for (int o=0;o<6;o++){ accO[o]=boff[o]; accS[o]=bscl[o]; }
  const float* a = act + (size_t)b*CDIM*NWIN + wpos;
  for (int c=0;c<CDIM;c++){
    float av = a[(size_t)c*NWIN];
    #pragma unroll
    for (int o=0;o<6;o++){ accO[o] += av*woff[o*CDIM+c]; accS[o] += av*wscl[o*CDIM+c]; }
  }
  #pragma unroll
  for (int h=0;h<NHEAD;h++){
    float4 r;
    r.x = accO[2*h]   * (1.f/16.f);
    r.y = accO[2*h+1] * (1.f/16.f);
    r.z = accS[2*h];
    r.w = accS[2*h+1];
    offscl[(size_t)(b*NHEAD+h)*NWIN + wpos] = r;
  }
}

// ---------- K3: qkv projection, hybrid: LDS A-path (R13) + global-W path (R15) ----------
// LDS = 40,960 B -> 4 blocks/CU; 2 barriers total (was 6).
__launch_bounds__(256)
__global__ void k_qkv_mfma(const float* __restrict__ x, const unsigned short* __restrict__ w16,
                           const float* __restrict__ bqkv,
                           unsigned short* __restrict__ q, unsigned short* __restrict__ kk,
                           unsigned short* __restrict__ v){
  __shared__ float xf[96*72];        // 27,648 B
  __shared__ uint4 xbf4[64*13];      // 13,312 B
  const int t = threadIdx.x;
  const int b = blockIdx.x / 196;
  const int p0 = (blockIdx.x % 196) * 64;

  // Phase A: coalesced f32 stage
  #pragma unroll
  for (int i=0;i<6;i++){
    int f = t + i*256; int c = f>>4; int p4 = (f&15)*4;
    *(float4*)(xf + c*72 + p4) = *(const float4*)(x + (size_t)(b*CDIM+c)*NPOS + p0 + p4);
  }
  __syncthreads();
  // Phase B: in-LDS transpose -> bf16 [pos][ch]
  #pragma unroll
  for (int i=0;i<3;i++){
    int u = t + i*256; int ps = u & 63; int oct = u >> 6;
    uint32_t pk0 = packbf(xf[(oct*8+0)*72+ps], xf[(oct*8+1)*72+ps]);
    uint32_t pk1 = packbf(xf[(oct*8+2)*72+ps], xf[(oct*8+3)*72+ps]);
    uint32_t pk2 = packbf(xf[(oct*8+4)*72+ps], xf[(oct*8+5)*72+ps]);
    uint32_t pk3 = packbf(xf[(oct*8+6)*72+ps], xf[(oct*8+7)*72+ps]);
    xbf4[ps*13 + oct] = make_uint4(pk0,pk1,pk2,pk3);
  }
  __syncthreads();

  const int lane = t & 63, wv = t >> 6;
  const int g = lane >> 4, r16 = lane & 15;
  const int pos = p0 + wv*16 + r16;

  for (int s=0;s<3;s++){
    f32x4 acc[6];
    #pragma unroll
    for (int nf=0;nf<6;nf++) acc[nf] = (f32x4){0.f,0.f,0.f,0.f};
    #pragma unroll
    for (int ks=0;ks<3;ks++){
      bf16x8 xb = *(const bf16x8*)&xbf4[(wv*16 + r16)*13 + ks*4 + g];   // B: col=pos
      #pragma unroll
      for (int nf=0;nf<6;nf++){
        uint4 wu = *(const uint4*)(w16 + ((size_t)(s*96 + nf*16 + r16)*96 + ks*32 + 8*g));
        acc[nf] = __builtin_amdgcn_mfma_f32_16x16x32_bf16(*(const bf16x8*)&wu, xb, acc[nf], 0,0,0);
      }
    }
    unsigned short* dst = (s==0)?q:((s==1)?kk:v);
    float sc = (s==0) ? SCALE : 1.f;
    #pragma unroll
    for (int nf=0;nf<6;nf++){
      int o0 = nf*16 + 4*g;
      int hh = o0 >> 5; int d0 = o0 & 31;
      float4 bv = *(const float4*)(bqkv + s*96 + o0);
      uint2 pk = make_uint2(packbf((acc[nf][0]+bv.x)*sc, (acc[nf][1]+bv.y)*sc),
                            packbf((acc[nf][2]+bv.z)*sc, (acc[nf][3]+bv.w)*sc));
      *(uint2*)(dst + ((size_t)(b*NHEAD+hh)*NPOS + pos)*DH + d0) = pk;
    }
  }
}

// ---------- K4 v3b: fused bilinear sample + window attention ----------
// FROZEN byte-identical to round 11/13/15 (passing). Six schedule
// perturbations (R6,7,8,10,12,14) each broke it with ~1e-3. Do not touch.
__launch_bounds__(128)
__global__ void k_attn_mfma(const unsigned short* __restrict__ qb,
                            const unsigned short* __restrict__ kb,
                            const unsigned short* __restrict__ vb,
                            const float4* __restrict__ offscl,
                            const float* __restrict__ bias_g,
                            float* __restrict__ aout){
  __shared__ unsigned short VT_all[2*2048];  // 8 KB: [wave][32 dh][64 pos] swizzled
  const int h   = blockIdx.x % 3;
  const int grp = blockIdx.x / 3;
  const int wv  = threadIdx.x >> 6;
  const int lane = threadIdx.x & 63;
  const int win = grp*2 + wv;
  const int b = win>>8, wh=(win>>4)&15, ww=win&15;
  const int bh = b*NHEAD + h;
  const int g = lane>>4, r16 = lane&15;
  unsigned short* VT_s = VT_all + wv*2048;

  // ---- Q fragments (B operand of S^T: col=q, k=ch) ----
  uint4 qf[4];
  #pragma unroll
  for (int qt=0;qt<4;qt++){
    int qq = qt*16 + r16; if (qq > 48) qq = 48;
    int qi = qq/7; int qj = qq - qi*7;
    size_t pos = (size_t)(wh*7+qi)*HW + ww*7 + qj;
    qf[qt] = *(const uint4*)(qb + ((size_t)bh*NPOS + pos)*DH + g*8);
  }

  // ---- phase 1: per-lane sample coords for kv pos = lane ----
  int ki = lane/7; int kj = lane - ki*7;
  uint32_t nbaddr[4]; float nbw[4];
  {
    float4 os = offscl[(size_t)bh*NWIN + (wh*16+ww)];
    float px = (float)(ww*7+kj) + (float)(kj-3)*os.z + 55.5f*os.x;
    float py = (float)(wh*7+ki) + (float)(ki-3)*os.w + 55.5f*os.y;
    float x0f = floorf(px), y0f = floorf(py);
    float fx = px-x0f, fy = py-y0f;
    int x0 = (int)x0f, y0 = (int)y0f;
    float wb[4] = {(1.f-fx)*(1.f-fy), fx*(1.f-fy), (1.f-fx)*fy, fx*fy};
    bool qok = lane < 49;
    #pragma unroll
    for (int nb=0;nb<4;nb++){
      int xi = x0 + (nb&1), yi = y0 + (nb>>1);
      int xc = min(max(xi,0),HW-1), yc = min(max(yi,0),HW-1);
      nbaddr[nb] = (uint32_t)(yc*HW + xc) * 64u;   // byte offset (64B rows)
      nbw[nb] = (qok && xi==xc && yi==yc) ? wb[nb] : 0.f;
    }
  }

  // ---- phase 2: team gather; K stays in registers, V -> VT_s ----
  const char* kb8 = (const char*)kb + (size_t)bh*NPOS*64;
  const char* vb8 = (const char*)vb + (size_t)bh*NPOS*64;
  uint4 kfrag[4];
  #pragma unroll
  for (int pp=0;pp<4;pp++){
    int spos = pp*16 + r16;                        // kv row this 4-lane team handles
    float ka[8], va[8];
    #pragma unroll
    for (int j=0;j<8;j++){ ka[j]=0.f; va[j]=0.f; }
    #pragma unroll
    for (int nb=0;nb<4;nb++){
      uint32_t a = (uint32_t)__shfl((int)nbaddr[nb], spos);
      float    w = __shfl(nbw[nb], spos);
      uint4 uk = *(const uint4*)(kb8 + a + g*16);
      uint4 uv = *(const uint4*)(vb8 + a + g*16);
      ka[0]+=w*bfbits_lo(uk.x); ka[1]+=w*bfbits_hi(uk.x);
      ka[2]+=w*bfbits_lo(uk.y); ka[3]+=w*bfbits_hi(uk.y);
      ka[4]+=w*bfbits_lo(uk.z); ka[5]+=w*bfbits_hi(uk.z);
      ka[6]+=w*bfbits_lo(uk.w); ka[7]+=w*bfbits_hi(uk.w);
      va[0]+=w*bfbits_lo(uv.x); va[1]+=w*bfbits_hi(uv.x);
      va[2]+=w*bfbits_lo(uv.y); va[3]+=w*bfbits_hi(uv.y);
      va[4]+=w*bfbits_lo(uv.z); va[5]+=w*bfbits_hi(uv.z);
      va[6]+=w*bfbits_lo(uv.w); va[7]+=w*bfbits_hi(uv.w);
    }
    // K A-fragment for at=pp: lane(r16,g) holds K[pp*16+r16][8g..8g+7]
    kfrag[pp] = make_uint4(packbf(ka[0],ka[1]), packbf(ka[2],ka[3]),
                           packbf(ka[4],ka[5]), packbf(ka[6],ka[7]));
    // VT_s: row d, slot = (pos>>3) ^ (d&7), elem = pos&7 (round-5 proven layout)
    #pragma unroll
    for (int j=0;j<8;j++){
      int d = g*8 + j;
      VT_s[d*64 + (((spos>>3) ^ (d&7))*8) + (spos&7)] = f2bf(va[j]);
    }
  }

  // Real barrier (2 waves): orders VT_s short-writes before bf16x8 reads
  // across the TBAA gap. sched_barrier as compiler-level insurance.
  __builtin_amdgcn_sched_barrier(0);
  __syncthreads();
  __builtin_amdgcn_sched_barrier(0);

  // ---- S^T = K * Q^T + bias ----
  const float* bias_h = bias_g + h*4096;
  f32x4 acc[4][4];                               // [at = k-tile][qt]
  #pragma unroll
  for (int qt=0;qt<4;qt++){
    int qq = qt*16 + r16;
    #pragma unroll
    for (int at=0;at<4;at++)
      acc[at][qt] = *(const f32x4*)(bias_h + qq*64 + at*16 + g*4);
  }
  #pragma unroll
  for (int at=0;at<4;at++){
    bf16x8 a = *(const bf16x8*)&kfrag[at];
    #pragma unroll
    for (int qt=0;qt<4;qt++)
      acc[at][qt] = __builtin_amdgcn_mfma_f32_16x16x32_bf16(a, *(const bf16x8*)&qf[qt], acc[at][qt], 0,0,0);
  }

  // ---- softmax over k (rows of S^T): in-lane 16 + 2 shfl ----
  #pragma unroll
  for (int qt=0;qt<4;qt++){
    float m = acc[0][qt][0];
    #pragma unroll
    for (int at=0;at<4;at++)
      #pragma unroll
      for (int rr=0;rr<4;rr++) m = fmaxf(m, acc[at][qt][rr]);
    m = fmaxf(m, __shfl_xor(m, 16));
    m = fmaxf(m, __shfl_xor(m, 32));
    float s = 0.f;
    #pragma unroll
    for (int at=0;at<4;at++)
      #pragma unroll
      for (int rr=0;rr<4;rr++){ float e = __expf(acc[at][qt][rr]-m); acc[at][qt][rr]=e; s+=e; }
    s += __shfl_xor(s, 16);
    s += __shfl_xor(s, 32);
    float rl = 1.f/s;
    #pragma unroll
    for (int at=0;at<4;at++)
      #pragma unroll
      for (int rr=0;rr<4;rr++) acc[at][qt][rr] *= rl;
  }

  // ---- pack P to bf16 pairs: lane(g_src,r16) holds k = at*16 + 4*g_src + rr ----
  uint32_t plo[4][4], phi[4][4];                 // [at][qt]
  #pragma unroll
  for (int at=0;at<4;at++)
    #pragma unroll
    for (int qt=0;qt<4;qt++){
      plo[at][qt] = packbf(acc[at][qt][0], acc[at][qt][1]);
      phi[at][qt] = packbf(acc[at][qt][2], acc[at][qt][3]);
    }

  // ---- O^T = V^T * P^T : A = V^T rows (VT_s), B = P^T via in-register shfl ----
  // B-frag (qt,kt): lane(r16,g) needs P[qt*16+r16][k = kt*32 + 8g + j], j=0..7.
  // Source: at = 2kt + (g>>1), g_src = (2g + (j>>2))&3.
  f32x4 o[2][4];                                 // [dt = d-tile][qt]
  #pragma unroll
  for (int dt=0;dt<2;dt++)
    #pragma unroll
    for (int qt=0;qt<4;qt++) o[dt][qt] = (f32x4){0.f,0.f,0.f,0.f};

  #pragma unroll
  for (int kt=0;kt<2;kt++){
    uint4 pfrag[4];
    const int s0 = ((2*g)&3)*16 + r16;
    const int s1 = ((2*g+1)&3)*16 + r16;
    const bool odd = (g & 2);
    #pragma unroll
    for (int qt=0;qt<4;qt++){
      uint32_t e_lo0 = (uint32_t)__shfl((int)plo[2*kt  ][qt], s0);
      uint32_t e_hi0 = (uint32_t)__shfl((int)phi[2*kt  ][qt], s0);
      uint32_t e_lo1 = (uint32_t)__shfl((int)plo[2*kt  ][qt], s1);
      uint32_t e_hi1 = (uint32_t)__shfl((int)phi[2*kt  ][qt], s1);
      uint32_t o_lo0 = (uint32_t)__shfl((int)plo[2*kt+1][qt], s0);
      uint32_t o_hi0 = (uint32_t)__shfl((int)phi[2*kt+1][qt], s0);
      uint32_t o_lo1 = (uint32_t)__shfl((int)plo[2*kt+1][qt], s1);
      uint32_t o_hi1 = (uint32_t)__shfl((int)phi[2*kt+1][qt], s1);
      pfrag[qt] = make_uint4(odd?o_lo0:e_lo0, odd?o_hi0:e_hi0,
                             odd?o_lo1:e_lo1, odd?o_hi1:e_hi1);
    }
    #pragma unroll
    for (int dt=0;dt<2;dt++){
      int d = dt*16 + r16;
      bf16x8 a = *(const bf16x8*)&VT_s[d*64 + (((kt*4+g) ^ (d&7))*8)];
      #pragma unroll
      for (int qt=0;qt<4;qt++)
        o[dt][qt] = __builtin_amdgcn_mfma_f32_16x16x32_bf16(a, *(const bf16x8*)&pfrag[qt], o[dt][qt], 0,0,0);
    }
  }

  // ---- store O^T: lane-col = q (few lines per instruction) ----
  float* outb = aout + ((size_t)b*CDIM + h*DH)*NPOS;
  #pragma unroll
  for (int qt=0;qt<4;qt++){
    int q = qt*16 + r16;
    if (q < 49){
      int qi = q/7; int qj = q - qi*7;
      size_t opix = (size_t)(wh*7+qi)*HW + ww*7 + qj;
      #pragma unroll
      for (int dt=0;dt<2;dt++)
        #pragma unroll
        for (int rr=0;rr<4;rr++){
          int d = dt*16 + g*4 + rr;
          outb[(size_t)d*NPOS + opix] = o[dt][qt][rr];
        }
    }
  }
}

// ---------- K5: output projection, hybrid (LDS A-path + global-W), IN PLACE ----------
// In-place safety: the WHOLE input slice is staged into xf in phase A; after
// the barriers all reads are from LDS/registers; stores follow.
__launch_bounds__(256)
__global__ void k_proj_mfma(const float* yin, const unsigned short* __restrict__ w16,
                            const float* __restrict__ bproj, float* yout){
  __shared__ float xf[96*72];
  __shared__ uint4 xbf4[64*13];
  const int t = threadIdx.x;
  const int b = blockIdx.x / 196;
  const int p0 = (blockIdx.x % 196) * 64;

  #pragma unroll
  for (int i=0;i<6;i++){
    int f = t + i*256; int c = f>>4; int p4 = (f&15)*4;
    *(float4*)(xf + c*72 + p4) = *(const float4*)(yin + (size_t)(b*CDIM+c)*NPOS + p0 + p4);
  }
  __syncthreads();
  #pragma unroll
  for (int i=0;i<3;i++){
    int u = t + i*256; int ps = u & 63; int oct = u >> 6;
    uint32_t pk0 = packbf(xf[(oct*8+0)*72+ps], xf[(oct*8+1)*72+ps]);
    uint32_t pk1 = packbf(xf[(oct*8+2)*72+ps], xf[(oct*8+3)*72+ps]);
    uint32_t pk2 = packbf(xf[(oct*8+4)*72+ps], xf[(oct*8+5)*72+ps]);
    uint32_t pk3 = packbf(xf[(oct*8+6)*72+ps], xf[(oct*8+7)*72+ps]);
    xbf4[ps*13 + oct] = make_uint4(pk0,pk1,pk2,pk3);
  }
  __syncthreads();

  const int lane = t & 63, wv = t >> 6;
  const int g = lane >> 4, r16 = lane & 15;
  const int pos = p0 + wv*16 + r16;
  f32x4 acc[6];
  #pragma unroll
  for (int nf=0;nf<6;nf++) acc[nf] = (f32x4){0.f,0.f,0.f,0.f};
  #pragma unroll
  for (int ks=0;ks<3;ks++){
    bf16x8 xb = *(const bf16x8*)&xbf4[(wv*16 + r16)*13 + ks*4 + g];     // B: col=pos
    #pragma unroll
    for (int nf=0;nf<6;nf++){
      uint4 wu = *(const uint4*)(w16 + ((size_t)(nf*16 + r16)*96 + ks*32 + 8*g));
      acc[nf] = __builtin_amdgcn_mfma_f32_16x16x32_bf16(*(const bf16x8*)&wu, xb, acc[nf], 0,0,0);
    }
  }
  #pragma unroll
  for (int nf=0;nf<6;nf++){
    int o0 = nf*16 + 4*g;
    float4 bv = *(const float4*)(bproj + o0);
    yout[(size_t)(b*CDIM+o0+0)*NPOS + pos] = acc[nf][0] + bv.x;
    yout[(size_t)(b*CDIM+o0+1)*NPOS + pos] = acc[nf][1] + bv.y;
    yout[(size_t)(b*CDIM+o0+2)*NPOS + pos] = acc[nf][2] + bv.z;
    yout[(size_t)(b*CDIM+o0+3)*NPOS + pos] = acc[nf][3] + bv.w;
  }
}

extern "C" void kernel_launch(void* const* d_in, const int* in_sizes, int n_in,
                              void* d_out, int out_size, void* d_ws, size_t ws_size,
                              hipStream_t stream) {
  const float* x      = (const float*)d_in[0];
  const float* w_qkv  = (const float*)d_in[1];
  const float* b_qkv  = (const float*)d_in[2];
  const float* w_off  = (const float*)d_in[3];
  const float* b_off  = (const float*)d_in[4];
  const float* w_scl  = (const float*)d_in[5];
  const float* b_scl  = (const float*)d_in[6];
  const float* rpb    = (const float*)d_in[7];
  const float* w_proj = (const float*)d_in[8];
  const float* b_proj = (const float*)d_in[9];

  char* ws = (char*)d_ws;
  float*   act    = (float*)(ws + 0);                  // 1,572,864 B
  float4*  offscl = (float4*)(ws + 1572864);           //   196,608 B
  float*   bias_g = (float*)(ws + 1769472);            //    49,152 B
  unsigned short* w16q = (unsigned short*)(ws + 1818624); // 55,296 B
  unsigned short* w16p = (unsigned short*)(ws + 1873920); // 18,432 B
  const size_t QKV_BYTES = (size_t)NB*NHEAD*NPOS*DH*2; // 38,535,168 B each
  unsigned short* qbuf = (unsigned short*)(ws + 2097152);
  unsigned short* kbuf = (unsigned short*)(ws + 2097152 + QKV_BYTES);
  unsigned short* vbuf = (unsigned short*)(ws + 2097152 + 2*QKV_BYTES);

  hipLaunchKernelGGL(k_pre,       dim3(108),  dim3(256), 0, stream, rpb, bias_g, w_qkv, w_proj, w16q, w16p);
  hipLaunchKernelGGL(k_pool_act,  dim3(1536), dim3(256), 0, stream, x, act);
  hipLaunchKernelGGL(k_offscl,    dim3(16),   dim3(256), 0, stream, act, w_off, b_off, w_scl, b_scl, offscl);
  hipLaunchKernelGGL(k_qkv_mfma,  dim3(16*196), dim3(256), 0, stream, x, w16q, b_qkv, qbuf, kbuf, vbuf);
  hipLaunchKernelGGL(k_attn_mfma, dim3(3*2048), dim3(128), 0, stream,
                     qbuf, kbuf, vbuf, offscl, bias_g, (float*)d_out);
  hipLaunchKernelGGL(k_proj_mfma, dim3(16*196), dim3(256), 0, stream,
                     (const float*)d_out, w16p, b_proj, (float*)d_out);
}

// Round 18
// 205.840 us; speedup vs baseline: 1.1803x; 1.1628x over previous
//
#include <hip/hip_runtime.h>
#include <hip/hip_bf16.h>
#include <stdint.h>

#define NB 16
#define CDIM 96
#define HW 112
#define NPOS (HW*HW)      // 12544
#define NHEAD 3
#define DH 32
#define WN 16
#define NWIN (WN*WN)
#define SCALE 0.17677669529663687f

typedef __attribute__((ext_vector_type(8))) short bf16x8;
typedef __attribute__((ext_vector_type(4))) float f32x4;

// ---------- bf16 helpers ----------
__device__ __forceinline__ float bfbits_lo(uint32_t w){ union{uint32_t u; float f;} a; a.u = w<<16; return a.f; }
__device__ __forceinline__ float bfbits_hi(uint32_t w){ union{uint32_t u; float f;} a; a.u = w & 0xFFFF0000u; return a.f; }
__device__ __forceinline__ uint32_t packbf(float x, float y){
  union{float f; uint32_t u;} a, b; a.f = x; b.f = y;
  uint32_t ua = a.u + 0x7FFFu + ((a.u>>16)&1u);
  uint32_t ub = b.u + 0x7FFFu + ((b.u>>16)&1u);
  return (ua>>16) | (ub & 0xFFFF0000u);
}
__device__ __forceinline__ unsigned short f2bf(float x){
  union{float f; uint32_t u;} a; a.f = x;
  return (unsigned short)((a.u + 0x7FFFu + ((a.u>>16)&1u))>>16);
}

// ---------- K1: 7x7 mean pool + leaky relu ----------
__global__ void k_pool_act(const float* __restrict__ x, float* __restrict__ act){
  int n = blockIdx.x*256 + threadIdx.x;
  int ww = n & 15; int wh = (n>>4)&15; int bc = n>>8;
  const float* src = x + (size_t)bc*NPOS + (size_t)(wh*7)*HW + ww*7;
  float s = 0.f;
  #pragma unroll
  for (int r=0;r<7;r++){
    const float* row = src + r*HW;
    s += row[0]+row[1]+row[2]+row[3]+row[4]+row[5]+row[6];
  }
  s *= (1.f/49.f);
  act[n] = s > 0.f ? s : 0.01f*s;
}

// ---------- K2: offsets / scales per window ----------
__global__ void k_offscl(const float* __restrict__ act,
                         const float* __restrict__ woff, const float* __restrict__ boff,
                         const float* __restrict__ wscl, const float* __restrict__ bscl,
                         float4* __restrict__ offscl){
  int n = blockIdx.x*256 + threadIdx.x;
  int b = n >> 8; int wpos = n & 255;
  float accO[6], accS[6];
  #pragma unroll
  for (int o=0;o<6;o++){ accO[o]=boff[o]; accS[o]=bscl[o]; }
  const float* a = act + (size_t)b*CDIM*NWIN + wpos;
  for (int c=0;c<CDIM;c++){
    float av = a[(size_t)c*NWIN];
    #pragma unroll
    for (int o=0;o<6;o++){ accO[o] += av*woff[o*CDIM+c]; accS[o] += av*wscl[o*CDIM+c]; }
  }
  #pragma unroll
  for (int h=0;h<NHEAD;h++){
    float4 r;
    r.x = accO[2*h]   * (1.f/16.f);
    r.y = accO[2*h+1] * (1.f/16.f);
    r.z = accS[2*h];
    r.w = accS[2*h+1];
    offscl[(size_t)(b*NHEAD+h)*NWIN + wpos] = r;
  }
}

// ---------- K2b: padded bias table [3][64 q][64 k]; k>=49 -> -1e30 ----------
__global__ void k_bias_pre(const float* __restrict__ rpb, float* __restrict__ bias_g){
  int n = blockIdx.x*256 + threadIdx.x;
  if (n >= 3*64*64) return;
  int h = n >> 12; int q = (n>>6)&63; int k = n&63;
  float v = -1e30f;
  if (k < 49){
    int qc = q < 49 ? q : 48;
    int qi = qc/7, qj = qc - (qc/7)*7;
    int ki = k/7,  kj = k - (k/7)*7;
    v = rpb[((qi-ki+6)*13 + (qj-kj+6))*3 + h];
  }
  bias_g[n] = v;
}

// ---------- K3: qkv projection via bf16 MFMA ----------
// Operand-SWAPPED: C'[out][pos] (lane col = pos), dense uint2 stores.
__launch_bounds__(256)
__global__ void k_qkv_mfma(const float* __restrict__ x, const float* __restrict__ wqkv,
                           const float* __restrict__ bqkv,
                           unsigned short* __restrict__ q, unsigned short* __restrict__ kk,
                           unsigned short* __restrict__ v){
  __shared__ float xf[96*72];
  __shared__ uint4 xbf4[64*13];
  __shared__ uint4 wbf4[96*13];
  const int t = threadIdx.x;
  const int b = blockIdx.x / 196;
  const int p0 = (blockIdx.x % 196) * 64;

  #pragma unroll
  for (int i=0;i<6;i++){
    int f = t + i*256; int c = f>>4; int p4 = (f&15)*4;
    *(float4*)(xf + c*72 + p4) = *(const float4*)(x + (size_t)(b*CDIM+c)*NPOS + p0 + p4);
  }
  __syncthreads();
  #pragma unroll
  for (int i=0;i<3;i++){
    int u = t + i*256; int pos = u & 63; int oct = u >> 6;
    uint32_t pk0 = packbf(xf[(oct*8+0)*72+pos], xf[(oct*8+1)*72+pos]);
    uint32_t pk1 = packbf(xf[(oct*8+2)*72+pos], xf[(oct*8+3)*72+pos]);
    uint32_t pk2 = packbf(xf[(oct*8+4)*72+pos], xf[(oct*8+5)*72+pos]);
    uint32_t pk3 = packbf(xf[(oct*8+6)*72+pos], xf[(oct*8+7)*72+pos]);
    xbf4[pos*13 + oct] = make_uint4(pk0,pk1,pk2,pk3);
  }

  const int lane = t & 63, wv = t >> 6;
  const int g = lane >> 4, r16 = lane & 15;
  const int pos = p0 + wv*16 + r16;              // this lane's output position

  for (int s=0;s<3;s++){
    if (s) __syncthreads();
    #pragma unroll
    for (int i=0;i<9;i++){
      int f = t + i*256; int o = f/24; int c4m = f%24;
      float4 wvv = *(const float4*)(wqkv + (size_t)(s*96+o)*CDIM + c4m*4);
      ((uint2*)wbf4)[o*26 + c4m] = make_uint2(packbf(wvv.x,wvv.y), packbf(wvv.z,wvv.w));
    }
    __syncthreads();

    f32x4 acc[6];
    #pragma unroll
    for (int nf=0;nf<6;nf++) acc[nf] = (f32x4){0.f,0.f,0.f,0.f};
    #pragma unroll
    for (int ks=0;ks<3;ks++){
      bf16x8 xb = *(const bf16x8*)&xbf4[(wv*16 + r16)*13 + ks*4 + g];   // B: col=pos
      #pragma unroll
      for (int nf=0;nf<6;nf++){
        bf16x8 wf = *(const bf16x8*)&wbf4[(nf*16 + r16)*13 + ks*4 + g]; // A: row=out
        acc[nf] = __builtin_amdgcn_mfma_f32_16x16x32_bf16(wf, xb, acc[nf], 0,0,0);
      }
    }
    unsigned short* dst = (s==0)?q:((s==1)?kk:v);
    float sc = (s==0) ? SCALE : 1.f;
    #pragma unroll
    for (int nf=0;nf<6;nf++){
      int o0 = nf*16 + 4*g;                      // 4 consecutive outs, same head
      int hh = o0 >> 5; int d0 = o0 & 31;
      float4 bv = *(const float4*)(bqkv + s*96 + o0);
      uint2 pk = make_uint2(packbf((acc[nf][0]+bv.x)*sc, (acc[nf][1]+bv.y)*sc),
                            packbf((acc[nf][2]+bv.z)*sc, (acc[nf][3]+bv.w)*sc));
      *(uint2*)(dst + ((size_t)(b*NHEAD+hh)*NPOS + pos)*DH + d0) = pk;
    }
  }
}

// ---------- K4 v3b: fused bilinear sample + window attention ----------
// FROZEN byte-identical to round 11/13 (full-validation passing). Seven
// perturbations (R6,7,8,10,12,14,17) each broke it; R17 showed the failure
// is replay-intermittent (race-like). Do not touch.
__launch_bounds__(128)
__global__ void k_attn_mfma(const unsigned short* __restrict__ qb,
                            const unsigned short* __restrict__ kb,
                            const unsigned short* __restrict__ vb,
                            const float4* __restrict__ offscl,
                            const float* __restrict__ bias_g,
                            float* __restrict__ aout){
  __shared__ unsigned short VT_all[2*2048];  // 8 KB: [wave][32 dh][64 pos] swizzled
  const int h   = blockIdx.x % 3;
  const int grp = blockIdx.x / 3;
  const int wv  = threadIdx.x >> 6;
  const int lane = threadIdx.x & 63;
  const int win = grp*2 + wv;
  const int b = win>>8, wh=(win>>4)&15, ww=win&15;
  const int bh = b*NHEAD + h;
  const int g = lane>>4, r16 = lane&15;
  unsigned short* VT_s = VT_all + wv*2048;

  // ---- Q fragments (B operand of S^T: col=q, k=ch) ----
  uint4 qf[4];
  #pragma unroll
  for (int qt=0;qt<4;qt++){
    int qq = qt*16 + r16; if (qq > 48) qq = 48;
    int qi = qq/7; int qj = qq - qi*7;
    size_t pos = (size_t)(wh*7+qi)*HW + ww*7 + qj;
    qf[qt] = *(const uint4*)(qb + ((size_t)bh*NPOS + pos)*DH + g*8);
  }

  // ---- phase 1: per-lane sample coords for kv pos = lane ----
  int ki = lane/7; int kj = lane - ki*7;
  uint32_t nbaddr[4]; float nbw[4];
  {
    float4 os = offscl[(size_t)bh*NWIN + (wh*16+ww)];
    float px = (float)(ww*7+kj) + (float)(kj-3)*os.z + 55.5f*os.x;
    float py = (float)(wh*7+ki) + (float)(ki-3)*os.w + 55.5f*os.y;
    float x0f = floorf(px), y0f = floorf(py);
    float fx = px-x0f, fy = py-y0f;
    int x0 = (int)x0f, y0 = (int)y0f;
    float wb[4] = {(1.f-fx)*(1.f-fy), fx*(1.f-fy), (1.f-fx)*fy, fx*fy};
    bool qok = lane < 49;
    #pragma unroll
    for (int nb=0;nb<4;nb++){
      int xi = x0 + (nb&1), yi = y0 + (nb>>1);
      int xc = min(max(xi,0),HW-1), yc = min(max(yi,0),HW-1);
      nbaddr[nb] = (uint32_t)(yc*HW + xc) * 64u;   // byte offset (64B rows)
      nbw[nb] = (qok && xi==xc && yi==yc) ? wb[nb] : 0.f;
    }
  }

  // ---- phase 2: team gather; K stays in registers, V -> VT_s ----
  const char* kb8 = (const char*)kb + (size_t)bh*NPOS*64;
  const char* vb8 = (const char*)vb + (size_t)bh*NPOS*64;
  uint4 kfrag[4];
  #pragma unroll
  for (int pp=0;pp<4;pp++){
    int spos = pp*16 + r16;                        // kv row this 4-lane team handles
    float ka[8], va[8];
    #pragma unroll
    for (int j=0;j<8;j++){ ka[j]=0.f; va[j]=0.f; }
    #pragma unroll
    for (int nb=0;nb<4;nb++){
      uint32_t a = (uint32_t)__shfl((int)nbaddr[nb], spos);
      float    w = __shfl(nbw[nb], spos);
      uint4 uk = *(const uint4*)(kb8 + a + g*16);
      uint4 uv = *(const uint4*)(vb8 + a + g*16);
      ka[0]+=w*bfbits_lo(uk.x); ka[1]+=w*bfbits_hi(uk.x);
      ka[2]+=w*bfbits_lo(uk.y); ka[3]+=w*bfbits_hi(uk.y);
      ka[4]+=w*bfbits_lo(uk.z); ka[5]+=w*bfbits_hi(uk.z);
      ka[6]+=w*bfbits_lo(uk.w); ka[7]+=w*bfbits_hi(uk.w);
      va[0]+=w*bfbits_lo(uv.x); va[1]+=w*bfbits_hi(uv.x);
      va[2]+=w*bfbits_lo(uv.y); va[3]+=w*bfbits_hi(uv.y);
      va[4]+=w*bfbits_lo(uv.z); va[5]+=w*bfbits_hi(uv.z);
      va[6]+=w*bfbits_lo(uv.w); va[7]+=w*bfbits_hi(uv.w);
    }
    // K A-fragment for at=pp: lane(r16,g) holds K[pp*16+r16][8g..8g+7]
    kfrag[pp] = make_uint4(packbf(ka[0],ka[1]), packbf(ka[2],ka[3]),
                           packbf(ka[4],ka[5]), packbf(ka[6],ka[7]));
    // VT_s: row d, slot = (pos>>3) ^ (d&7), elem = pos&7 (round-5 proven layout)
    #pragma unroll
    for (int j=0;j<8;j++){
      int d = g*8 + j;
      VT_s[d*64 + (((spos>>3) ^ (d&7))*8) + (spos&7)] = f2bf(va[j]);
    }
  }

  // Real barrier (2 waves): orders VT_s short-writes before bf16x8 reads
  // across the TBAA gap. sched_barrier as compiler-level insurance.
  __builtin_amdgcn_sched_barrier(0);
  __syncthreads();
  __builtin_amdgcn_sched_barrier(0);

  // ---- S^T = K * Q^T + bias ----
  const float* bias_h = bias_g + h*4096;
  f32x4 acc[4][4];                               // [at = k-tile][qt]
  #pragma unroll
  for (int qt=0;qt<4;qt++){
    int qq = qt*16 + r16;
    #pragma unroll
    for (int at=0;at<4;at++)
      acc[at][qt] = *(const f32x4*)(bias_h + qq*64 + at*16 + g*4);
  }
  #pragma unroll
  for (int at=0;at<4;at++){
    bf16x8 a = *(const bf16x8*)&kfrag[at];
    #pragma unroll
    for (int qt=0;qt<4;qt++)
      acc[at][qt] = __builtin_amdgcn_mfma_f32_16x16x32_bf16(a, *(const bf16x8*)&qf[qt], acc[at][qt], 0,0,0);
  }

  // ---- softmax over k (rows of S^T): in-lane 16 + 2 shfl ----
  #pragma unroll
  for (int qt=0;qt<4;qt++){
    float m = acc[0][qt][0];
    #pragma unroll
    for (int at=0;at<4;at++)
      #pragma unroll
      for (int rr=0;rr<4;rr++) m = fmaxf(m, acc[at][qt][rr]);
    m = fmaxf(m, __shfl_xor(m, 16));
    m = fmaxf(m, __shfl_xor(m, 32));
    float s = 0.f;
    #pragma unroll
    for (int at=0;at<4;at++)
      #pragma unroll
      for (int rr=0;rr<4;rr++){ float e = __expf(acc[at][qt][rr]-m); acc[at][qt][rr]=e; s+=e; }
    s += __shfl_xor(s, 16);
    s += __shfl_xor(s, 32);
    float rl = 1.f/s;
    #pragma unroll
    for (int at=0;at<4;at++)
      #pragma unroll
      for (int rr=0;rr<4;rr++) acc[at][qt][rr] *= rl;
  }

  // ---- pack P to bf16 pairs: lane(g_src,r16) holds k = at*16 + 4*g_src + rr ----
  uint32_t plo[4][4], phi[4][4];                 // [at][qt]
  #pragma unroll
  for (int at=0;at<4;at++)
    #pragma unroll
    for (int qt=0;qt<4;qt++){
      plo[at][qt] = packbf(acc[at][qt][0], acc[at][qt][1]);
      phi[at][qt] = packbf(acc[at][qt][2], acc[at][qt][3]);
    }

  // ---- O^T = V^T * P^T : A = V^T rows (VT_s), B = P^T via in-register shfl ----
  // B-frag (qt,kt): lane(r16,g) needs P[qt*16+r16][k = kt*32 + 8g + j], j=0..7.
  // Source: at = 2kt + (g>>1), g_src = (2g + (j>>2))&3.
  f32x4 o[2][4];                                 // [dt = d-tile][qt]
  #pragma unroll
  for (int dt=0;dt<2;dt++)
    #pragma unroll
    for (int qt=0;qt<4;qt++) o[dt][qt] = (f32x4){0.f,0.f,0.f,0.f};

  #pragma unroll
  for (int kt=0;kt<2;kt++){
    uint4 pfrag[4];
    const int s0 = ((2*g)&3)*16 + r16;
    const int s1 = ((2*g+1)&3)*16 + r16;
    const bool odd = (g & 2);
    #pragma unroll
    for (int qt=0;qt<4;qt++){
      uint32_t e_lo0 = (uint32_t)__shfl((int)plo[2*kt  ][qt], s0);
      uint32_t e_hi0 = (uint32_t)__shfl((int)phi[2*kt  ][qt], s0);
      uint32_t e_lo1 = (uint32_t)__shfl((int)plo[2*kt  ][qt], s1);
      uint32_t e_hi1 = (uint32_t)__shfl((int)phi[2*kt  ][qt], s1);
      uint32_t o_lo0 = (uint32_t)__shfl((int)plo[2*kt+1][qt], s0);
      uint32_t o_hi0 = (uint32_t)__shfl((int)phi[2*kt+1][qt], s0);
      uint32_t o_lo1 = (uint32_t)__shfl((int)plo[2*kt+1][qt], s1);
      uint32_t o_hi1 = (uint32_t)__shfl((int)phi[2*kt+1][qt], s1);
      pfrag[qt] = make_uint4(odd?o_lo0:e_lo0, odd?o_hi0:e_hi0,
                             odd?o_lo1:e_lo1, odd?o_hi1:e_hi1);
    }
    #pragma unroll
    for (int dt=0;dt<2;dt++){
      int d = dt*16 + r16;
      bf16x8 a = *(const bf16x8*)&VT_s[d*64 + (((kt*4+g) ^ (d&7))*8)];
      #pragma unroll
      for (int qt=0;qt<4;qt++)
        o[dt][qt] = __builtin_amdgcn_mfma_f32_16x16x32_bf16(a, *(const bf16x8*)&pfrag[qt], o[dt][qt], 0,0,0);
    }
  }

  // ---- store O^T: lane-col = q (few lines per instruction) ----
  float* outb = aout + ((size_t)b*CDIM + h*DH)*NPOS;
  #pragma unroll
  for (int qt=0;qt<4;qt++){
    int q = qt*16 + r16;
    if (q < 49){
      int qi = q/7; int qj = q - qi*7;
      size_t opix = (size_t)(wh*7+qi)*HW + ww*7 + qj;
      #pragma unroll
      for (int dt=0;dt<2;dt++)
        #pragma unroll
        for (int rr=0;rr<4;rr++){
          int d = dt*16 + g*4 + rr;
          outb[(size_t)d*NPOS + opix] = o[dt][qt][rr];
        }
    }
  }
}

// ---------- K5: output projection via bf16 MFMA, IN PLACE on d_out ----------
// Operand-SWAPPED: C'[out][pos] -> lane col = pos -> dense stores.
__launch_bounds__(256)
__global__ void k_proj_mfma(const float* yin, const float* __restrict__ wproj,
                            const float* __restrict__ bproj, float* yout){
  __shared__ float xf[96*72];
  __shared__ uint4 xbf4[64*13];
  __shared__ uint4 wbf4[96*13];
  const int t = threadIdx.x;
  const int b = blockIdx.x / 196;
  const int p0 = (blockIdx.x % 196) * 64;

  #pragma unroll
  for (int i=0;i<6;i++){
    int f = t + i*256; int c = f>>4; int p4 = (f&15)*4;
    *(float4*)(xf + c*72 + p4) = *(const float4*)(yin + (size_t)(b*CDIM+c)*NPOS + p0 + p4);
  }
  __syncthreads();
  #pragma unroll
  for (int i=0;i<3;i++){
    int u = t + i*256; int pos = u & 63; int oct = u >> 6;
    uint32_t pk0 = packbf(xf[(oct*8+0)*72+pos], xf[(oct*8+1)*72+pos]);
    uint32_t pk1 = packbf(xf[(oct*8+2)*72+pos], xf[(oct*8+3)*72+pos]);
    uint32_t pk2 = packbf(xf[(oct*8+4)*72+pos], xf[(oct*8+5)*72+pos]);
    uint32_t pk3 = packbf(xf[(oct*8+6)*72+pos], xf[(oct*8+7)*72+pos]);
    xbf4[pos*13 + oct] = make_uint4(pk0,pk1,pk2,pk3);
  }
  #pragma unroll
  for (int i=0;i<9;i++){
    int f = t + i*256; int o = f/24; int c4m = f%24;
    float4 wvv = *(const float4*)(wproj + (size_t)o*CDIM + c4m*4);
    ((uint2*)wbf4)[o*26 + c4m] = make_uint2(packbf(wvv.x,wvv.y), packbf(wvv.z,wvv.w));
  }
  __syncthreads();

  const int lane = t & 63, wv = t >> 6;
  const int g = lane >> 4, r16 = lane & 15;
  const int pos = p0 + wv*16 + r16;
  f32x4 acc[6];
  #pragma unroll
  for (int nf=0;nf<6;nf++) acc[nf] = (f32x4){0.f,0.f,0.f,0.f};
  #pragma unroll
  for (int ks=0;ks<3;ks++){
    bf16x8 xb = *(const bf16x8*)&xbf4[(wv*16 + r16)*13 + ks*4 + g];     // B: col=pos
    #pragma unroll
    for (int nf=0;nf<6;nf++){
      bf16x8 wf = *(const bf16x8*)&wbf4[(nf*16 + r16)*13 + ks*4 + g];   // A: row=out
      acc[nf] = __builtin_amdgcn_mfma_f32_16x16x32_bf16(wf, xb, acc[nf], 0,0,0);
    }
  }
  #pragma unroll
  for (int nf=0;nf<6;nf++){
    int o0 = nf*16 + 4*g;
    float4 bv = *(const float4*)(bproj + o0);
    yout[(size_t)(b*CDIM+o0+0)*NPOS + pos] = acc[nf][0] + bv.x;
    yout[(size_t)(b*CDIM+o0+1)*NPOS + pos] = acc[nf][1] + bv.y;
    yout[(size_t)(b*CDIM+o0+2)*NPOS + pos] = acc[nf][2] + bv.z;
    yout[(size_t)(b*CDIM+o0+3)*NPOS + pos] = acc[nf][3] + bv.w;
  }
}

extern "C" void kernel_launch(void* const* d_in, const int* in_sizes, int n_in,
                              void* d_out, int out_size, void* d_ws, size_t ws_size,
                              hipStream_t stream) {
  const float* x      = (const float*)d_in[0];
  const float* w_qkv  = (const float*)d_in[1];
  const float* b_qkv  = (const float*)d_in[2];
  const float* w_off  = (const float*)d_in[3];
  const float* b_off  = (const float*)d_in[4];
  const float* w_scl  = (const float*)d_in[5];
  const float* b_scl  = (const float*)d_in[6];
  const float* rpb    = (const float*)d_in[7];
  const float* w_proj = (const float*)d_in[8];
  const float* b_proj = (const float*)d_in[9];

  char* ws = (char*)d_ws;
  float*   act    = (float*)(ws + 0);                  // 1,572,864 B
  float4*  offscl = (float4*)(ws + 1572864);           //   196,608 B
  float*   bias_g = (float*)(ws + 1769472);            //    49,152 B
  const size_t QKV_BYTES = (size_t)NB*NHEAD*NPOS*DH*2; // 38,535,168 B each
  unsigned short* qbuf = (unsigned short*)(ws + 2097152);
  unsigned short* kbuf = (unsigned short*)(ws + 2097152 + QKV_BYTES);
  unsigned short* vbuf = (unsigned short*)(ws + 2097152 + 2*QKV_BYTES);

  hipLaunchKernelGGL(k_pool_act,  dim3(1536), dim3(256), 0, stream, x, act);
  hipLaunchKernelGGL(k_offscl,    dim3(16),   dim3(256), 0, stream, act, w_off, b_off, w_scl, b_scl, offscl);
  hipLaunchKernelGGL(k_bias_pre,  dim3(48),   dim3(256), 0, stream, rpb, bias_g);
  hipLaunchKernelGGL(k_qkv_mfma,  dim3(16*196), dim3(256), 0, stream, x, w_qkv, b_qkv, qbuf, kbuf, vbuf);
  hipLaunchKernelGGL(k_attn_mfma, dim3(3*2048), dim3(128), 0, stream,
                     qbuf, kbuf, vbuf, offscl, bias_g, (float*)d_out);
  hipLaunchKernelGGL(k_proj_mfma, dim3(16*196), dim3(256), 0, stream,
                     (const float*)d_out, w_proj, b_proj, (float*)d_out);
}

// Round 19
// 204.913 us; speedup vs baseline: 1.1857x; 1.0045x over previous
//
#include <hip/hip_runtime.h>
#include <hip/hip_bf16.h>
#include <stdint.h>

#define NB 16
#define CDIM 96
#define HW 112
#define NPOS (HW*HW)      // 12544
#define NHEAD 3
#define DH 32
#define WN 16
#define NWIN (WN*WN)
#define SCALE 0.17677669529663687f

typedef __attribute__((ext_vector_type(8))) short bf16x8;
typedef __attribute__((ext_vector_type(4))) float f32x4;

// ---------- bf16 helpers ----------
__device__ __forceinline__ float bfbits_lo(uint32_t w){ union{uint32_t u; float f;} a; a.u = w<<16; return a.f; }
__device__ __forceinline__ float bfbits_hi(uint32_t w){ union{uint32_t u; float f;} a; a.u = w & 0xFFFF0000u; return a.f; }
__device__ __forceinline__ uint32_t packbf(float x, float y){
  union{float f; uint32_t u;} a, b; a.f = x; b.f = y;
  uint32_t ua = a.u + 0x7FFFu + ((a.u>>16)&1u);
  uint32_t ub = b.u + 0x7FFFu + ((b.u>>16)&1u);
  return (ua>>16) | (ub & 0xFFFF0000u);
}
__device__ __forceinline__ unsigned short f2bf(float x){
  union{float f; uint32_t u;} a; a.f = x;
  return (unsigned short)((a.u + 0x7FFFu + ((a.u>>16)&1u))>>16);
}

// ---------- K1: 7x7 mean pool + leaky relu ----------
__global__ void k_pool_act(const float* __restrict__ x, float* __restrict__ act){
  int n = blockIdx.x*256 + threadIdx.x;
  int ww = n & 15; int wh = (n>>4)&15; int bc = n>>8;
  const float* src = x + (size_t)bc*NPOS + (size_t)(wh*7)*HW + ww*7;
  float s = 0.f;
  #pragma unroll
  for (int r=0;r<7;r++){
    const float* row = src + r*HW;
    s += row[0]+row[1]+row[2]+row[3]+row[4]+row[5]+row[6];
  }
  s *= (1.f/49.f);
  act[n] = s > 0.f ? s : 0.01f*s;
}

// ---------- K2: offsets / scales per window ----------
__global__ void k_offscl(const float* __restrict__ act,
                         const float* __restrict__ woff, const float* __restrict__ boff,
                         const float* __restrict__ wscl, const float* __restrict__ bscl,
                         float4* __restrict__ offscl){
  int n = blockIdx.x*256 + threadIdx.x;
  int b = n >> 8; int wpos = n & 255;
  float accO[6], accS[6];
  #pragma unroll
  for (int o=0;o<6;o++){ accO[o]=boff[o]; accS[o]=bscl[o]; }
  const float* a = act + (size_t)b*CDIM*NWIN + wpos;
  for (int c=0;c<CDIM;c++){
    float av = a[(size_t)c*NWIN];
    #pragma unroll
    for (int o=0;o<6;o++){ accO[o] += av*woff[o*CDIM+c]; accS[o] += av*wscl[o*CDIM+c]; }
  }
  #pragma unroll
  for (int h=0;h<NHEAD;h++){
    float4 r;
    r.x = accO[2*h]   * (1.f/16.f);
    r.y = accO[2*h+1] * (1.f/16.f);
    r.z = accS[2*h];
    r.w = accS[2*h+1];
    offscl[(size_t)(b*NHEAD+h)*NWIN + wpos] = r;
  }
}

// ---------- K2b: padded bias table [3][64 q][64 k]; k>=49 -> -1e30 ----------
__global__ void k_bias_pre(const float* __restrict__ rpb, float* __restrict__ bias_g){
  int n = blockIdx.x*256 + threadIdx.x;
  if (n >= 3*64*64) return;
  int h = n >> 12; int q = (n>>6)&63; int k = n&63;
  float v = -1e30f;
  if (k < 49){
    int qc = q < 49 ? q : 48;
    int qi = qc/7, qj = qc - (qc/7)*7;
    int ki = k/7,  kj = k - (k/7)*7;
    v = rpb[((qi-ki+6)*13 + (qj-kj+6))*3 + h];
  }
  bias_g[n] = v;
}

// ---------- K3: qkv projection via bf16 MFMA ----------
// Barrier-collapsed: xf's bytes are DEAD after the transpose, so all 288 W
// rows are staged ONCE into that region (guarded by a real __syncthreads at
// every typed-region transition -- the R9-proven ordering mechanism).
// Barriers 7 -> 3; W staged 1x not 3x. LDS 73,216 B -> still 2 blocks/CU.
__launch_bounds__(256)
__global__ void k_qkv_mfma(const float* __restrict__ x, const float* __restrict__ wqkv,
                           const float* __restrict__ bqkv,
                           unsigned short* __restrict__ q, unsigned short* __restrict__ kk,
                           unsigned short* __restrict__ v){
  __shared__ char smem[73216];
  float* xf   = (float*)smem;                    // bytes 0..27,647 (phases A/B)
  uint2* wbf2 = (uint2*)smem;                    // bytes 0..59,903 (after xf dies)
  uint4* wbf4 = (uint4*)smem;
  uint4* xbf4 = (uint4*)(smem + 59904);          // bytes 59,904..73,215 (no overlap with xf)
  const int t = threadIdx.x;
  const int b = blockIdx.x / 196;
  const int p0 = (blockIdx.x % 196) * 64;

  // Phase A: coalesced f32 stage of the x tile
  #pragma unroll
  for (int i=0;i<6;i++){
    int f = t + i*256; int c = f>>4; int p4 = (f&15)*4;
    *(float4*)(xf + c*72 + p4) = *(const float4*)(x + (size_t)(b*CDIM+c)*NPOS + p0 + p4);
  }
  __syncthreads();
  // Phase B: in-LDS transpose -> bf16 [pos][ch] (xbf4 region, disjoint from xf)
  #pragma unroll
  for (int i=0;i<3;i++){
    int u = t + i*256; int pos = u & 63; int oct = u >> 6;
    uint32_t pk0 = packbf(xf[(oct*8+0)*72+pos], xf[(oct*8+1)*72+pos]);
    uint32_t pk1 = packbf(xf[(oct*8+2)*72+pos], xf[(oct*8+3)*72+pos]);
    uint32_t pk2 = packbf(xf[(oct*8+4)*72+pos], xf[(oct*8+5)*72+pos]);
    uint32_t pk3 = packbf(xf[(oct*8+6)*72+pos], xf[(oct*8+7)*72+pos]);
    xbf4[pos*13 + oct] = make_uint4(pk0,pk1,pk2,pk3);
  }
  // BARRIER: all xf reads complete before W overwrites xf's bytes.
  __syncthreads();

  // Stage ALL 288 W rows once (27 float4 loads/thread, latency overlapped)
  #pragma unroll
  for (int i=0;i<27;i++){
    int f = t + i*256; int o = f/24; int c4m = f%24;      // o = 0..287
    float4 wvv = *(const float4*)(wqkv + (size_t)o*CDIM + c4m*4);
    wbf2[o*26 + c4m] = make_uint2(packbf(wvv.x,wvv.y), packbf(wvv.z,wvv.w));
  }
  __syncthreads();

  const int lane = t & 63, wv = t >> 6;
  const int g = lane >> 4, r16 = lane & 15;
  const int pos = p0 + wv*16 + r16;

  for (int s=0;s<3;s++){
    f32x4 acc[6];
    #pragma unroll
    for (int nf=0;nf<6;nf++) acc[nf] = (f32x4){0.f,0.f,0.f,0.f};
    #pragma unroll
    for (int ks=0;ks<3;ks++){
      bf16x8 xb = *(const bf16x8*)&xbf4[(wv*16 + r16)*13 + ks*4 + g];   // B: col=pos
      #pragma unroll
      for (int nf=0;nf<6;nf++){
        bf16x8 wf = *(const bf16x8*)&wbf4[(s*96 + nf*16 + r16)*13 + ks*4 + g]; // A: row=out
        acc[nf] = __builtin_amdgcn_mfma_f32_16x16x32_bf16(wf, xb, acc[nf], 0,0,0);
      }
    }
    unsigned short* dst = (s==0)?q:((s==1)?kk:v);
    float sc = (s==0) ? SCALE : 1.f;
    #pragma unroll
    for (int nf=0;nf<6;nf++){
      int o0 = nf*16 + 4*g;                      // 4 consecutive outs, same head
      int hh = o0 >> 5; int d0 = o0 & 31;
      float4 bv = *(const float4*)(bqkv + s*96 + o0);
      uint2 pk = make_uint2(packbf((acc[nf][0]+bv.x)*sc, (acc[nf][1]+bv.y)*sc),
                            packbf((acc[nf][2]+bv.z)*sc, (acc[nf][3]+bv.w)*sc));
      *(uint2*)(dst + ((size_t)(b*NHEAD+hh)*NPOS + pos)*DH + d0) = pk;
    }
  }
}

// ---------- K4 v3b: fused bilinear sample + window attention ----------
// FROZEN byte-identical to round 11/13/18 (full-validation passing). Eight
// perturbations (R6,7,8,10,12,14,17) broke it; failure is replay-intermittent
// (race-like). Do not touch.
__launch_bounds__(128)
__global__ void k_attn_mfma(const unsigned short* __restrict__ qb,
                            const unsigned short* __restrict__ kb,
                            const unsigned short* __restrict__ vb,
                            const float4* __restrict__ offscl,
                            const float* __restrict__ bias_g,
                            float* __restrict__ aout){
  __shared__ unsigned short VT_all[2*2048];  // 8 KB: [wave][32 dh][64 pos] swizzled
  const int h   = blockIdx.x % 3;
  const int grp = blockIdx.x / 3;
  const int wv  = threadIdx.x >> 6;
  const int lane = threadIdx.x & 63;
  const int win = grp*2 + wv;
  const int b = win>>8, wh=(win>>4)&15, ww=win&15;
  const int bh = b*NHEAD + h;
  const int g = lane>>4, r16 = lane&15;
  unsigned short* VT_s = VT_all + wv*2048;

  // ---- Q fragments (B operand of S^T: col=q, k=ch) ----
  uint4 qf[4];
  #pragma unroll
  for (int qt=0;qt<4;qt++){
    int qq = qt*16 + r16; if (qq > 48) qq = 48;
    int qi = qq/7; int qj = qq - qi*7;
    size_t pos = (size_t)(wh*7+qi)*HW + ww*7 + qj;
    qf[qt] = *(const uint4*)(qb + ((size_t)bh*NPOS + pos)*DH + g*8);
  }

  // ---- phase 1: per-lane sample coords for kv pos = lane ----
  int ki = lane/7; int kj = lane - ki*7;
  uint32_t nbaddr[4]; float nbw[4];
  {
    float4 os = offscl[(size_t)bh*NWIN + (wh*16+ww)];
    float px = (float)(ww*7+kj) + (float)(kj-3)*os.z + 55.5f*os.x;
    float py = (float)(wh*7+ki) + (float)(ki-3)*os.w + 55.5f*os.y;
    float x0f = floorf(px), y0f = floorf(py);
    float fx = px-x0f, fy = py-y0f;
    int x0 = (int)x0f, y0 = (int)y0f;
    float wb[4] = {(1.f-fx)*(1.f-fy), fx*(1.f-fy), (1.f-fx)*fy, fx*fy};
    bool qok = lane < 49;
    #pragma unroll
    for (int nb=0;nb<4;nb++){
      int xi = x0 + (nb&1), yi = y0 + (nb>>1);
      int xc = min(max(xi,0),HW-1), yc = min(max(yi,0),HW-1);
      nbaddr[nb] = (uint32_t)(yc*HW + xc) * 64u;   // byte offset (64B rows)
      nbw[nb] = (qok && xi==xc && yi==yc) ? wb[nb] : 0.f;
    }
  }

  // ---- phase 2: team gather; K stays in registers, V -> VT_s ----
  const char* kb8 = (const char*)kb + (size_t)bh*NPOS*64;
  const char* vb8 = (const char*)vb + (size_t)bh*NPOS*64;
  uint4 kfrag[4];
  #pragma unroll
  for (int pp=0;pp<4;pp++){
    int spos = pp*16 + r16;                        // kv row this 4-lane team handles
    float ka[8], va[8];
    #pragma unroll
    for (int j=0;j<8;j++){ ka[j]=0.f; va[j]=0.f; }
    #pragma unroll
    for (int nb=0;nb<4;nb++){
      uint32_t a = (uint32_t)__shfl((int)nbaddr[nb], spos);
      float    w = __shfl(nbw[nb], spos);
      uint4 uk = *(const uint4*)(kb8 + a + g*16);
      uint4 uv = *(const uint4*)(vb8 + a + g*16);
      ka[0]+=w*bfbits_lo(uk.x); ka[1]+=w*bfbits_hi(uk.x);
      ka[2]+=w*bfbits_lo(uk.y); ka[3]+=w*bfbits_hi(uk.y);
      ka[4]+=w*bfbits_lo(uk.z); ka[5]+=w*bfbits_hi(uk.z);
      ka[6]+=w*bfbits_lo(uk.w); ka[7]+=w*bfbits_hi(uk.w);
      va[0]+=w*bfbits_lo(uv.x); va[1]+=w*bfbits_hi(uv.x);
      va[2]+=w*bfbits_lo(uv.y); va[3]+=w*bfbits_hi(uv.y);
      va[4]+=w*bfbits_lo(uv.z); va[5]+=w*bfbits_hi(uv.z);
      va[6]+=w*bfbits_lo(uv.w); va[7]+=w*bfbits_hi(uv.w);
    }
    // K A-fragment for at=pp: lane(r16,g) holds K[pp*16+r16][8g..8g+7]
    kfrag[pp] = make_uint4(packbf(ka[0],ka[1]), packbf(ka[2],ka[3]),
                           packbf(ka[4],ka[5]), packbf(ka[6],ka[7]));
    // VT_s: row d, slot = (pos>>3) ^ (d&7), elem = pos&7 (round-5 proven layout)
    #pragma unroll
    for (int j=0;j<8;j++){
      int d = g*8 + j;
      VT_s[d*64 + (((spos>>3) ^ (d&7))*8) + (spos&7)] = f2bf(va[j]);
    }
  }

  // Real barrier (2 waves): orders VT_s short-writes before bf16x8 reads
  // across the TBAA gap. sched_barrier as compiler-level insurance.
  __builtin_amdgcn_sched_barrier(0);
  __syncthreads();
  __builtin_amdgcn_sched_barrier(0);

  // ---- S^T = K * Q^T + bias ----
  const float* bias_h = bias_g + h*4096;
  f32x4 acc[4][4];                               // [at = k-tile][qt]
  #pragma unroll
  for (int qt=0;qt<4;qt++){
    int qq = qt*16 + r16;
    #pragma unroll
    for (int at=0;at<4;at++)
      acc[at][qt] = *(const f32x4*)(bias_h + qq*64 + at*16 + g*4);
  }
  #pragma unroll
  for (int at=0;at<4;at++){
    bf16x8 a = *(const bf16x8*)&kfrag[at];
    #pragma unroll
    for (int qt=0;qt<4;qt++)
      acc[at][qt] = __builtin_amdgcn_mfma_f32_16x16x32_bf16(a, *(const bf16x8*)&qf[qt], acc[at][qt], 0,0,0);
  }

  // ---- softmax over k (rows of S^T): in-lane 16 + 2 shfl ----
  #pragma unroll
  for (int qt=0;qt<4;qt++){
    float m = acc[0][qt][0];
    #pragma unroll
    for (int at=0;at<4;at++)
      #pragma unroll
      for (int rr=0;rr<4;rr++) m = fmaxf(m, acc[at][qt][rr]);
    m = fmaxf(m, __shfl_xor(m, 16));
    m = fmaxf(m, __shfl_xor(m, 32));
    float s = 0.f;
    #pragma unroll
    for (int at=0;at<4;at++)
      #pragma unroll
      for (int rr=0;rr<4;rr++){ float e = __expf(acc[at][qt][rr]-m); acc[at][qt][rr]=e; s+=e; }
    s += __shfl_xor(s, 16);
    s += __shfl_xor(s, 32);
    float rl = 1.f/s;
    #pragma unroll
    for (int at=0;at<4;at++)
      #pragma unroll
      for (int rr=0;rr<4;rr++) acc[at][qt][rr] *= rl;
  }

  // ---- pack P to bf16 pairs: lane(g_src,r16) holds k = at*16 + 4*g_src + rr ----
  uint32_t plo[4][4], phi[4][4];                 // [at][qt]
  #pragma unroll
  for (int at=0;at<4;at++)
    #pragma unroll
    for (int qt=0;qt<4;qt++){
      plo[at][qt] = packbf(acc[at][qt][0], acc[at][qt][1]);
      phi[at][qt] = packbf(acc[at][qt][2], acc[at][qt][3]);
    }

  // ---- O^T = V^T * P^T : A = V^T rows (VT_s), B = P^T via in-register shfl ----
  // B-frag (qt,kt): lane(r16,g) needs P[qt*16+r16][k = kt*32 + 8g + j], j=0..7.
  // Source: at = 2kt + (g>>1), g_src = (2g + (j>>2))&3.
  f32x4 o[2][4];                                 // [dt = d-tile][qt]
  #pragma unroll
  for (int dt=0;dt<2;dt++)
    #pragma unroll
    for (int qt=0;qt<4;qt++) o[dt][qt] = (f32x4){0.f,0.f,0.f,0.f};

  #pragma unroll
  for (int kt=0;kt<2;kt++){
    uint4 pfrag[4];
    const int s0 = ((2*g)&3)*16 + r16;
    const int s1 = ((2*g+1)&3)*16 + r16;
    const bool odd = (g & 2);
    #pragma unroll
    for (int qt=0;qt<4;qt++){
      uint32_t e_lo0 = (uint32_t)__shfl((int)plo[2*kt  ][qt], s0);
      uint32_t e_hi0 = (uint32_t)__shfl((int)phi[2*kt  ][qt], s0);
      uint32_t e_lo1 = (uint32_t)__shfl((int)plo[2*kt  ][qt], s1);
      uint32_t e_hi1 = (uint32_t)__shfl((int)phi[2*kt  ][qt], s1);
      uint32_t o_lo0 = (uint32_t)__shfl((int)plo[2*kt+1][qt], s0);
      uint32_t o_hi0 = (uint32_t)__shfl((int)phi[2*kt+1][qt], s0);
      uint32_t o_lo1 = (uint32_t)__shfl((int)plo[2*kt+1][qt], s1);
      uint32_t o_hi1 = (uint32_t)__shfl((int)phi[2*kt+1][qt], s1);
      pfrag[qt] = make_uint4(odd?o_lo0:e_lo0, odd?o_hi0:e_hi0,
                             odd?o_lo1:e_lo1, odd?o_hi1:e_hi1);
    }
    #pragma unroll
    for (int dt=0;dt<2;dt++){
      int d = dt*16 + r16;
      bf16x8 a = *(const bf16x8*)&VT_s[d*64 + (((kt*4+g) ^ (d&7))*8)];
      #pragma unroll
      for (int qt=0;qt<4;qt++)
        o[dt][qt] = __builtin_amdgcn_mfma_f32_16x16x32_bf16(a, *(const bf16x8*)&pfrag[qt], o[dt][qt], 0,0,0);
    }
  }

  // ---- store O^T: lane-col = q (few lines per instruction) ----
  float* outb = aout + ((size_t)b*CDIM + h*DH)*NPOS;
  #pragma unroll
  for (int qt=0;qt<4;qt++){
    int q = qt*16 + r16;
    if (q < 49){
      int qi = q/7; int qj = q - qi*7;
      size_t opix = (size_t)(wh*7+qi)*HW + ww*7 + qj;
      #pragma unroll
      for (int dt=0;dt<2;dt++)
        #pragma unroll
        for (int rr=0;rr<4;rr++){
          int d = dt*16 + g*4 + rr;
          outb[(size_t)d*NPOS + opix] = o[dt][qt][rr];
        }
    }
  }
}

// ---------- K5: output projection via bf16 MFMA, IN PLACE on d_out ----------
// Operand-SWAPPED: C'[out][pos] -> lane col = pos -> dense stores. (R13 exact)
__launch_bounds__(256)
__global__ void k_proj_mfma(const float* yin, const float* __restrict__ wproj,
                            const float* __restrict__ bproj, float* yout){
  __shared__ float xf[96*72];
  __shared__ uint4 xbf4[64*13];
  __shared__ uint4 wbf4[96*13];
  const int t = threadIdx.x;
  const int b = blockIdx.x / 196;
  const int p0 = (blockIdx.x % 196) * 64;

  #pragma unroll
  for (int i=0;i<6;i++){
    int f = t + i*256; int c = f>>4; int p4 = (f&15)*4;
    *(float4*)(xf + c*72 + p4) = *(const float4*)(yin + (size_t)(b*CDIM+c)*NPOS + p0 + p4);
  }
  __syncthreads();
  #pragma unroll
  for (int i=0;i<3;i++){
    int u = t + i*256; int pos = u & 63; int oct = u >> 6;
    uint32_t pk0 = packbf(xf[(oct*8+0)*72+pos], xf[(oct*8+1)*72+pos]);
    uint32_t pk1 = packbf(xf[(oct*8+2)*72+pos], xf[(oct*8+3)*72+pos]);
    uint32_t pk2 = packbf(xf[(oct*8+4)*72+pos], xf[(oct*8+5)*72+pos]);
    uint32_t pk3 = packbf(xf[(oct*8+6)*72+pos], xf[(oct*8+7)*72+pos]);
    xbf4[pos*13 + oct] = make_uint4(pk0,pk1,pk2,pk3);
  }
  #pragma unroll
  for (int i=0;i<9;i++){
    int f = t + i*256; int o = f/24; int c4m = f%24;
    float4 wvv = *(const float4*)(wproj + (size_t)o*CDIM + c4m*4);
    ((uint2*)wbf4)[o*26 + c4m] = make_uint2(packbf(wvv.x,wvv.y), packbf(wvv.z,wvv.w));
  }
  __syncthreads();

  const int lane = t & 63, wv = t >> 6;
  const int g = lane >> 4, r16 = lane & 15;
  const int pos = p0 + wv*16 + r16;
  f32x4 acc[6];
  #pragma unroll
  for (int nf=0;nf<6;nf++) acc[nf] = (f32x4){0.f,0.f,0.f,0.f};
  #pragma unroll
  for (int ks=0;ks<3;ks++){
    bf16x8 xb = *(const bf16x8*)&xbf4[(wv*16 + r16)*13 + ks*4 + g];     // B: col=pos
    #pragma unroll
    for (int nf=0;nf<6;nf++){
      bf16x8 wf = *(const bf16x8*)&wbf4[(nf*16 + r16)*13 + ks*4 + g];   // A: row=out
      acc[nf] = __builtin_amdgcn_mfma_f32_16x16x32_bf16(wf, xb, acc[nf], 0,0,0);
    }
  }
  #pragma unroll
  for (int nf=0;nf<6;nf++){
    int o0 = nf*16 + 4*g;
    float4 bv = *(const float4*)(bproj + o0);
    yout[(size_t)(b*CDIM+o0+0)*NPOS + pos] = acc[nf][0] + bv.x;
    yout[(size_t)(b*CDIM+o0+1)*NPOS + pos] = acc[nf][1] + bv.y;
    yout[(size_t)(b*CDIM+o0+2)*NPOS + pos] = acc[nf][2] + bv.z;
    yout[(size_t)(b*CDIM+o0+3)*NPOS + pos] = acc[nf][3] + bv.w;
  }
}

extern "C" void kernel_launch(void* const* d_in, const int* in_sizes, int n_in,
                              void* d_out, int out_size, void* d_ws, size_t ws_size,
                              hipStream_t stream) {
  const float* x      = (const float*)d_in[0];
  const float* w_qkv  = (const float*)d_in[1];
  const float* b_qkv  = (const float*)d_in[2];
  const float* w_off  = (const float*)d_in[3];
  const float* b_off  = (const float*)d_in[4];
  const float* w_scl  = (const float*)d_in[5];
  const float* b_scl  = (const float*)d_in[6];
  const float* rpb    = (const float*)d_in[7];
  const float* w_proj = (const float*)d_in[8];
  const float* b_proj = (const float*)d_in[9];

  char* ws = (char*)d_ws;
  float*   act    = (float*)(ws + 0);                  // 1,572,864 B
  float4*  offscl = (float4*)(ws + 1572864);           //   196,608 B
  float*   bias_g = (float*)(ws + 1769472);            //    49,152 B
  const size_t QKV_BYTES = (size_t)NB*NHEAD*NPOS*DH*2; // 38,535,168 B each
  unsigned short* qbuf = (unsigned short*)(ws + 2097152);
  unsigned short* kbuf = (unsigned short*)(ws + 2097152 + QKV_BYTES);
  unsigned short* vbuf = (unsigned short*)(ws + 2097152 + 2*QKV_BYTES);

  hipLaunchKernelGGL(k_pool_act,  dim3(1536), dim3(256), 0, stream, x, act);
  hipLaunchKernelGGL(k_offscl,    dim3(16),   dim3(256), 0, stream, act, w_off, b_off, w_scl, b_scl, offscl);
  hipLaunchKernelGGL(k_bias_pre,  dim3(48),   dim3(256), 0, stream, rpb, bias_g);
  hipLaunchKernelGGL(k_qkv_mfma,  dim3(16*196), dim3(256), 0, stream, x, w_qkv, b_qkv, qbuf, kbuf, vbuf);
  hipLaunchKernelGGL(k_attn_mfma, dim3(3*2048), dim3(128), 0, stream,
                     qbuf, kbuf, vbuf, offscl, bias_g, (float*)d_out);
  hipLaunchKernelGGL(k_proj_mfma, dim3(16*196), dim3(256), 0, stream,
                     (const float*)d_out, w_proj, b_proj, (float*)d_out);
}

// Round 21
// 202.821 us; speedup vs baseline: 1.1979x; 1.0103x over previous
//
#include <hip/hip_runtime.h>
#include <hip/hip_bf16.h>
#include <stdint.h>

#define NB 16
#define CDIM 96
#define HW 112
#define NPOS (HW*HW)      // 12544
#define NHEAD 3
#define DH 32
#define WN 16
#define NWIN (WN*WN)
#define SCALE 0.17677669529663687f

typedef __attribute__((ext_vector_type(8))) short bf16x8;
typedef __attribute__((ext_vector_type(4))) float f32x4;

// ---------- bf16 helpers ----------
__device__ __forceinline__ float bfbits_lo(uint32_t w){ union{uint32_t u; float f;} a; a.u = w<<16; return a.f; }
__device__ __forceinline__ float bfbits_hi(uint32_t w){ union{uint32_t u; float f;} a; a.u = w & 0xFFFF0000u; return a.f; }
__device__ __forceinline__ uint32_t packbf(float x, float y){
  union{float f; uint32_t u;} a, b; a.f = x; b.f = y;
  uint32_t ua = a.u + 0x7FFFu + ((a.u>>16)&1u);
  uint32_t ub = b.u + 0x7FFFu + ((b.u>>16)&1u);
  return (ua>>16) | (ub & 0xFFFF0000u);
}
__device__ __forceinline__ unsigned short f2bf(float x){
  union{float f; uint32_t u;} a; a.f = x;
  return (unsigned short)((a.u + 0x7FFFu + ((a.u>>16)&1u))>>16);
}

// ---------- K1: 7x7 mean pool + leaky relu ----------
__global__ void k_pool_act(const float* __restrict__ x, float* __restrict__ act){
  int n = blockIdx.x*256 + threadIdx.x;
  int ww = n & 15; int wh = (n>>4)&15; int bc = n>>8;
  const float* src = x + (size_t)bc*NPOS + (size_t)(wh*7)*HW + ww*7;
  float s = 0.f;
  #pragma unroll
  for (int r=0;r<7;r++){
    const float* row = src + r*HW;
    s += row[0]+row[1]+row[2]+row[3]+row[4]+row[5]+row[6];
  }
  s *= (1.f/49.f);
  act[n] = s > 0.f ? s : 0.01f*s;
}

// ---------- K2: offsets / scales per window ----------
__global__ void k_offscl(const float* __restrict__ act,
                         const float* __restrict__ woff, const float* __restrict__ boff,
                         const float* __restrict__ wscl, const float* __restrict__ bscl,
                         float4* __restrict__ offscl){
  int n = blockIdx.x*256 + threadIdx.x;
  int b = n >> 8; int wpos = n & 255;
  float accO[6], accS[6];
  #pragma unroll
  for (int o=0;o<6;o++){ accO[o]=boff[o]; accS[o]=bscl[o]; }
  const float* a = act + (size_t)b*CDIM*NWIN + wpos;
  for (int c=0;c<CDIM;c++){
    float av = a[(size_t)c*NWIN];
    #pragma unroll
    for (int o=0;o<6;o++){ accO[o] += av*woff[o*CDIM+c]; accS[o] += av*wscl[o*CDIM+c]; }
  }
  #pragma unroll
  for (int h=0;h<NHEAD;h++){
    float4 r;
    r.x = accO[2*h]   * (1.f/16.f);
    r.y = accO[2*h+1] * (1.f/16.f);
    r.z = accS[2*h];
    r.w = accS[2*h+1];
    offscl[(size_t)(b*NHEAD+h)*NWIN + wpos] = r;
  }
}

// ---------- K2b: padded bias table [3][64 q][64 k]; k>=49 -> -1e30 ----------
__global__ void k_bias_pre(const float* __restrict__ rpb, float* __restrict__ bias_g){
  int n = blockIdx.x*256 + threadIdx.x;
  if (n >= 3*64*64) return;
  int h = n >> 12; int q = (n>>6)&63; int k = n&63;
  float v = -1e30f;
  if (k < 49){
    int qc = q < 49 ? q : 48;
    int qi = qc/7, qj = qc - (qc/7)*7;
    int ki = k/7,  kj = k - (k/7)*7;
    v = rpb[((qi-ki+6)*13 + (qj-kj+6))*3 + h];
  }
  bias_g[n] = v;
}

// ---------- K3: qkv projection via bf16 MFMA ----------
// Operand-SWAPPED: C'[out][pos] (lane col = pos), dense uint2 stores.
// Separate __shared__ arrays, no LDS byte-region reuse (the only structure
// that has passed full validation twice: R13, R18).
__launch_bounds__(256)
__global__ void k_qkv_mfma(const float* __restrict__ x, const float* __restrict__ wqkv,
                           const float* __restrict__ bqkv,
                           unsigned short* __restrict__ q, unsigned short* __restrict__ kk,
                           unsigned short* __restrict__ v){
  __shared__ float xf[96*72];
  __shared__ uint4 xbf4[64*13];
  __shared__ uint4 wbf4[96*13];
  const int t = threadIdx.x;
  const int b = blockIdx.x / 196;
  const int p0 = (blockIdx.x % 196) * 64;

  #pragma unroll
  for (int i=0;i<6;i++){
    int f = t + i*256; int c = f>>4; int p4 = (f&15)*4;
    *(float4*)(xf + c*72 + p4) = *(const float4*)(x + (size_t)(b*CDIM+c)*NPOS + p0 + p4);
  }
  __syncthreads();
  #pragma unroll
  for (int i=0;i<3;i++){
    int u = t + i*256; int pos = u & 63; int oct = u >> 6;
    uint32_t pk0 = packbf(xf[(oct*8+0)*72+pos], xf[(oct*8+1)*72+pos]);
    uint32_t pk1 = packbf(xf[(oct*8+2)*72+pos], xf[(oct*8+3)*72+pos]);
    uint32_t pk2 = packbf(xf[(oct*8+4)*72+pos], xf[(oct*8+5)*72+pos]);
    uint32_t pk3 = packbf(xf[(oct*8+6)*72+pos], xf[(oct*8+7)*72+pos]);
    xbf4[pos*13 + oct] = make_uint4(pk0,pk1,pk2,pk3);
  }

  const int lane = t & 63, wv = t >> 6;
  const int g = lane >> 4, r16 = lane & 15;
  const int pos = p0 + wv*16 + r16;              // this lane's output position

  for (int s=0;s<3;s++){
    if (s) __syncthreads();
    #pragma unroll
    for (int i=0;i<9;i++){
      int f = t + i*256; int o = f/24; int c4m = f%24;
      float4 wvv = *(const float4*)(wqkv + (size_t)(s*96+o)*CDIM + c4m*4);
      ((uint2*)wbf4)[o*26 + c4m] = make_uint2(packbf(wvv.x,wvv.y), packbf(wvv.z,wvv.w));
    }
    __syncthreads();

    f32x4 acc[6];
    #pragma unroll
    for (int nf=0;nf<6;nf++) acc[nf] = (f32x4){0.f,0.f,0.f,0.f};
    #pragma unroll
    for (int ks=0;ks<3;ks++){
      bf16x8 xb = *(const bf16x8*)&xbf4[(wv*16 + r16)*13 + ks*4 + g];   // B: col=pos
      #pragma unroll
      for (int nf=0;nf<6;nf++){
        bf16x8 wf = *(const bf16x8*)&wbf4[(nf*16 + r16)*13 + ks*4 + g]; // A: row=out
        acc[nf] = __builtin_amdgcn_mfma_f32_16x16x32_bf16(wf, xb, acc[nf], 0,0,0);
      }
    }
    unsigned short* dst = (s==0)?q:((s==1)?kk:v);
    float sc = (s==0) ? SCALE : 1.f;
    #pragma unroll
    for (int nf=0;nf<6;nf++){
      int o0 = nf*16 + 4*g;                      // 4 consecutive outs, same head
      int hh = o0 >> 5; int d0 = o0 & 31;
      float4 bv = *(const float4*)(bqkv + s*96 + o0);
      uint2 pk = make_uint2(packbf((acc[nf][0]+bv.x)*sc, (acc[nf][1]+bv.y)*sc),
                            packbf((acc[nf][2]+bv.z)*sc, (acc[nf][3]+bv.w)*sc));
      *(uint2*)(dst + ((size_t)(b*NHEAD+hh)*NPOS + pos)*DH + d0) = pk;
    }
  }
}

// ---------- K4 v3b: fused bilinear sample + window attention ----------
// FROZEN byte-identical to round 11/13/18 (full-validation passing). Many
// perturbations broke it (replay-intermittent race). Do not touch.
__launch_bounds__(128)
__global__ void k_attn_mfma(const unsigned short* __restrict__ qb,
                            const unsigned short* __restrict__ kb,
                            const unsigned short* __restrict__ vb,
                            const float4* __restrict__ offscl,
                            const float* __restrict__ bias_g,
                            float* __restrict__ aout){
  __shared__ unsigned short VT_all[2*2048];  // 8 KB: [wave][32 dh][64 pos] swizzled
  const int h   = blockIdx.x % 3;
  const int grp = blockIdx.x / 3;
  const int wv  = threadIdx.x >> 6;
  const int lane = threadIdx.x & 63;
  const int win = grp*2 + wv;
  const int b = win>>8, wh=(win>>4)&15, ww=win&15;
  const int bh = b*NHEAD + h;
  const int g = lane>>4, r16 = lane&15;
  unsigned short* VT_s = VT_all + wv*2048;

  // ---- Q fragments (B operand of S^T: col=q, k=ch) ----
  uint4 qf[4];
  #pragma unroll
  for (int qt=0;qt<4;qt++){
    int qq = qt*16 + r16; if (qq > 48) qq = 48;
    int qi = qq/7; int qj = qq - qi*7;
    size_t pos = (size_t)(wh*7+qi)*HW + ww*7 + qj;
    qf[qt] = *(const uint4*)(qb + ((size_t)bh*NPOS + pos)*DH + g*8);
  }

  // ---- phase 1: per-lane sample coords for kv pos = lane ----
  int ki = lane/7; int kj = lane - ki*7;
  uint32_t nbaddr[4]; float nbw[4];
  {
    float4 os = offscl[(size_t)bh*NWIN + (wh*16+ww)];
    float px = (float)(ww*7+kj) + (float)(kj-3)*os.z + 55.5f*os.x;
    float py = (float)(wh*7+ki) + (float)(ki-3)*os.w + 55.5f*os.y;
    float x0f = floorf(px), y0f = floorf(py);
    float fx = px-x0f, fy = py-y0f;
    int x0 = (int)x0f, y0 = (int)y0f;
    float wb[4] = {(1.f-fx)*(1.f-fy), fx*(1.f-fy), (1.f-fx)*fy, fx*fy};
    bool qok = lane < 49;
    #pragma unroll
    for (int nb=0;nb<4;nb++){
      int xi = x0 + (nb&1), yi = y0 + (nb>>1);
      int xc = min(max(xi,0),HW-1), yc = min(max(yi,0),HW-1);
      nbaddr[nb] = (uint32_t)(yc*HW + xc) * 64u;   // byte offset (64B rows)
      nbw[nb] = (qok && xi==xc && yi==yc) ? wb[nb] : 0.f;
    }
  }

  // ---- phase 2: team gather; K stays in registers, V -> VT_s ----
  const char* kb8 = (const char*)kb + (size_t)bh*NPOS*64;
  const char* vb8 = (const char*)vb + (size_t)bh*NPOS*64;
  uint4 kfrag[4];
  #pragma unroll
  for (int pp=0;pp<4;pp++){
    int spos = pp*16 + r16;                        // kv row this 4-lane team handles
    float ka[8], va[8];
    #pragma unroll
    for (int j=0;j<8;j++){ ka[j]=0.f; va[j]=0.f; }
    #pragma unroll
    for (int nb=0;nb<4;nb++){
      uint32_t a = (uint32_t)__shfl((int)nbaddr[nb], spos);
      float    w = __shfl(nbw[nb], spos);
      uint4 uk = *(const uint4*)(kb8 + a + g*16);
      uint4 uv = *(const uint4*)(vb8 + a + g*16);
      ka[0]+=w*bfbits_lo(uk.x); ka[1]+=w*bfbits_hi(uk.x);
      ka[2]+=w*bfbits_lo(uk.y); ka[3]+=w*bfbits_hi(uk.y);
      ka[4]+=w*bfbits_lo(uk.z); ka[5]+=w*bfbits_hi(uk.z);
      ka[6]+=w*bfbits_lo(uk.w); ka[7]+=w*bfbits_hi(uk.w);
      va[0]+=w*bfbits_lo(uv.x); va[1]+=w*bfbits_hi(uv.x);
      va[2]+=w*bfbits_lo(uv.y); va[3]+=w*bfbits_hi(uv.y);
      va[4]+=w*bfbits_lo(uv.z); va[5]+=w*bfbits_hi(uv.z);
      va[6]+=w*bfbits_lo(uv.w); va[7]+=w*bfbits_hi(uv.w);
    }
    // K A-fragment for at=pp: lane(r16,g) holds K[pp*16+r16][8g..8g+7]
    kfrag[pp] = make_uint4(packbf(ka[0],ka[1]), packbf(ka[2],ka[3]),
                           packbf(ka[4],ka[5]), packbf(ka[6],ka[7]));
    // VT_s: row d, slot = (pos>>3) ^ (d&7), elem = pos&7 (round-5 proven layout)
    #pragma unroll
    for (int j=0;j<8;j++){
      int d = g*8 + j;
      VT_s[d*64 + (((spos>>3) ^ (d&7))*8) + (spos&7)] = f2bf(va[j]);
    }
  }

  // Real barrier (2 waves): orders VT_s short-writes before bf16x8 reads
  // across the TBAA gap. sched_barrier as compiler-level insurance.
  __builtin_amdgcn_sched_barrier(0);
  __syncthreads();
  __builtin_amdgcn_sched_barrier(0);

  // ---- S^T = K * Q^T + bias ----
  const float* bias_h = bias_g + h*4096;
  f32x4 acc[4][4];                               // [at = k-tile][qt]
  #pragma unroll
  for (int qt=0;qt<4;qt++){
    int qq = qt*16 + r16;
    #pragma unroll
    for (int at=0;at<4;at++)
      acc[at][qt] = *(const f32x4*)(bias_h + qq*64 + at*16 + g*4);
  }
  #pragma unroll
  for (int at=0;at<4;at++){
    bf16x8 a = *(const bf16x8*)&kfrag[at];
    #pragma unroll
    for (int qt=0;qt<4;qt++)
      acc[at][qt] = __builtin_amdgcn_mfma_f32_16x16x32_bf16(a, *(const bf16x8*)&qf[qt], acc[at][qt], 0,0,0);
  }

  // ---- softmax over k (rows of S^T): in-lane 16 + 2 shfl ----
  #pragma unroll
  for (int qt=0;qt<4;qt++){
    float m = acc[0][qt][0];
    #pragma unroll
    for (int at=0;at<4;at++)
      #pragma unroll
      for (int rr=0;rr<4;rr++) m = fmaxf(m, acc[at][qt][rr]);
    m = fmaxf(m, __shfl_xor(m, 16));
    m = fmaxf(m, __shfl_xor(m, 32));
    float s = 0.f;
    #pragma unroll
    for (int at=0;at<4;at++)
      #pragma unroll
      for (int rr=0;rr<4;rr++){ float e = __expf(acc[at][qt][rr]-m); acc[at][qt][rr]=e; s+=e; }
    s += __shfl_xor(s, 16);
    s += __shfl_xor(s, 32);
    float rl = 1.f/s;
    #pragma unroll
    for (int at=0;at<4;at++)
      #pragma unroll
      for (int rr=0;rr<4;rr++) acc[at][qt][rr] *= rl;
  }

  // ---- pack P to bf16 pairs: lane(g_src,r16) holds k = at*16 + 4*g_src + rr ----
  uint32_t plo[4][4], phi[4][4];                 // [at][qt]
  #pragma unroll
  for (int at=0;at<4;at++)
    #pragma unroll
    for (int qt=0;qt<4;qt++){
      plo[at][qt] = packbf(acc[at][qt][0], acc[at][qt][1]);
      phi[at][qt] = packbf(acc[at][qt][2], acc[at][qt][3]);
    }

  // ---- O^T = V^T * P^T : A = V^T rows (VT_s), B = P^T via in-register shfl ----
  // B-frag (qt,kt): lane(r16,g) needs P[qt*16+r16][k = kt*32 + 8g + j], j=0..7.
  // Source: at = 2kt + (g>>1), g_src = (2g + (j>>2))&3.
  f32x4 o[2][4];                                 // [dt = d-tile][qt]
  #pragma unroll
  for (int dt=0;dt<2;dt++)
    #pragma unroll
    for (int qt=0;qt<4;qt++) o[dt][qt] = (f32x4){0.f,0.f,0.f,0.f};

  #pragma unroll
  for (int kt=0;kt<2;kt++){
    uint4 pfrag[4];
    const int s0 = ((2*g)&3)*16 + r16;
    const int s1 = ((2*g+1)&3)*16 + r16;
    const bool odd = (g & 2);
    #pragma unroll
    for (int qt=0;qt<4;qt++){
      uint32_t e_lo0 = (uint32_t)__shfl((int)plo[2*kt  ][qt], s0);
      uint32_t e_hi0 = (uint32_t)__shfl((int)phi[2*kt  ][qt], s0);
      uint32_t e_lo1 = (uint32_t)__shfl((int)plo[2*kt  ][qt], s1);
      uint32_t e_hi1 = (uint32_t)__shfl((int)phi[2*kt  ][qt], s1);
      uint32_t o_lo0 = (uint32_t)__shfl((int)plo[2*kt+1][qt], s0);
      uint32_t o_hi0 = (uint32_t)__shfl((int)phi[2*kt+1][qt], s0);
      uint32_t o_lo1 = (uint32_t)__shfl((int)plo[2*kt+1][qt], s1);
      uint32_t o_hi1 = (uint32_t)__shfl((int)phi[2*kt+1][qt], s1);
      pfrag[qt] = make_uint4(odd?o_lo0:e_lo0, odd?o_hi0:e_hi0,
                             odd?o_lo1:e_lo1, odd?o_hi1:e_hi1);
    }
    #pragma unroll
    for (int dt=0;dt<2;dt++){
      int d = dt*16 + r16;
      bf16x8 a = *(const bf16x8*)&VT_s[d*64 + (((kt*4+g) ^ (d&7))*8)];
      #pragma unroll
      for (int qt=0;qt<4;qt++)
        o[dt][qt] = __builtin_amdgcn_mfma_f32_16x16x32_bf16(a, *(const bf16x8*)&pfrag[qt], o[dt][qt], 0,0,0);
    }
  }

  // ---- store O^T: lane-col = q (few lines per instruction) ----
  float* outb = aout + ((size_t)b*CDIM + h*DH)*NPOS;
  #pragma unroll
  for (int qt=0;qt<4;qt++){
    int q = qt*16 + r16;
    if (q < 49){
      int qi = q/7; int qj = q - qi*7;
      size_t opix = (size_t)(wh*7+qi)*HW + ww*7 + qj;
      #pragma unroll
      for (int dt=0;dt<2;dt++)
        #pragma unroll
        for (int rr=0;rr<4;rr++){
          int d = dt*16 + g*4 + rr;
          outb[(size_t)d*NPOS + opix] = o[dt][qt][rr];
        }
    }
  }
}

// ---------- K5: output projection via bf16 MFMA, IN PLACE on d_out ----------
// Operand-SWAPPED: C'[out][pos] -> lane col = pos -> dense stores.
__launch_bounds__(256)
__global__ void k_proj_mfma(const float* yin, const float* __restrict__ wproj,
                            const float* __restrict__ bproj, float* yout){
  __shared__ float xf[96*72];
  __shared__ uint4 xbf4[64*13];
  __shared__ uint4 wbf4[96*13];
  const int t = threadIdx.x;
  const int b = blockIdx.x / 196;
  const int p0 = (blockIdx.x % 196) * 64;

  #pragma unroll
  for (int i=0;i<6;i++){
    int f = t + i*256; int c = f>>4; int p4 = (f&15)*4;
    *(float4*)(xf + c*72 + p4) = *(const float4*)(yin + (size_t)(b*CDIM+c)*NPOS + p0 + p4);
  }
  __syncthreads();
  #pragma unroll
  for (int i=0;i<3;i++){
    int u = t + i*256; int pos = u & 63; int oct = u >> 6;
    uint32_t pk0 = packbf(xf[(oct*8+0)*72+pos], xf[(oct*8+1)*72+pos]);
    uint32_t pk1 = packbf(xf[(oct*8+2)*72+pos], xf[(oct*8+3)*72+pos]);
    uint32_t pk2 = packbf(xf[(oct*8+4)*72+pos], xf[(oct*8+5)*72+pos]);
    uint32_t pk3 = packbf(xf[(oct*8+6)*72+pos], xf[(oct*8+7)*72+pos]);
    xbf4[pos*13 + oct] = make_uint4(pk0,pk1,pk2,pk3);
  }
  #pragma unroll
  for (int i=0;i<9;i++){
    int f = t + i*256; int o = f/24; int c4m = f%24;
    float4 wvv = *(const float4*)(wproj + (size_t)o*CDIM + c4m*4);
    ((uint2*)wbf4)[o*26 + c4m] = make_uint2(packbf(wvv.x,wvv.y), packbf(wvv.z,wvv.w));
  }
  __syncthreads();

  const int lane = t & 63, wv = t >> 6;
  const int g = lane >> 4, r16 = lane & 15;
  const int pos = p0 + wv*16 + r16;
  f32x4 acc[6];
  #pragma unroll
  for (int nf=0;nf<6;nf++) acc[nf] = (f32x4){0.f,0.f,0.f,0.f};
  #pragma unroll
  for (int ks=0;ks<3;ks++){
    bf16x8 xb = *(const bf16x8*)&xbf4[(wv*16 + r16)*13 + ks*4 + g];     // B: col=pos
    #pragma unroll
    for (int nf=0;nf<6;nf++){
      bf16x8 wf = *(const bf16x8*)&wbf4[(nf*16 + r16)*13 + ks*4 + g];   // A: row=out
      acc[nf] = __builtin_amdgcn_mfma_f32_16x16x32_bf16(wf, xb, acc[nf], 0,0,0);
    }
  }
  #pragma unroll
  for (int nf=0;nf<6;nf++){
    int o0 = nf*16 + 4*g;
    float4 bv = *(const float4*)(bproj + o0);
    yout[(size_t)(b*CDIM+o0+0)*NPOS + pos] = acc[nf][0] + bv.x;
    yout[(size_t)(b*CDIM+o0+1)*NPOS + pos] = acc[nf][1] + bv.y;
    yout[(size_t)(b*CDIM+o0+2)*NPOS + pos] = acc[nf][2] + bv.z;
    yout[(size_t)(b*CDIM+o0+3)*NPOS + pos] = acc[nf][3] + bv.w;
  }
}

extern "C" void kernel_launch(void* const* d_in, const int* in_sizes, int n_in,
                              void* d_out, int out_size, void* d_ws, size_t ws_size,
                              hipStream_t stream) {
  const float* x      = (const float*)d_in[0];
  const float* w_qkv  = (const float*)d_in[1];
  const float* b_qkv  = (const float*)d_in[2];
  const float* w_off  = (const float*)d_in[3];
  const float* b_off  = (const float*)d_in[4];
  const float* w_scl  = (const float*)d_in[5];
  const float* b_scl  = (const float*)d_in[6];
  const float* rpb    = (const float*)d_in[7];
  const float* w_proj = (const float*)d_in[8];
  const float* b_proj = (const float*)d_in[9];

  char* ws = (char*)d_ws;
  float*   act    = (float*)(ws + 0);                  // 1,572,864 B
  float4*  offscl = (float4*)(ws + 1572864);           //   196,608 B
  float*   bias_g = (float*)(ws + 1769472);            //    49,152 B
  const size_t QKV_BYTES = (size_t)NB*NHEAD*NPOS*DH*2; // 38,535,168 B each
  unsigned short* qbuf = (unsigned short*)(ws + 2097152);
  unsigned short* kbuf = (unsigned short*)(ws + 2097152 + QKV_BYTES);
  unsigned short* vbuf = (unsigned short*)(ws + 2097152 + 2*QKV_BYTES);

  hipLaunchKernelGGL(k_pool_act,  dim3(1536), dim3(256), 0, stream, x, act);
  hipLaunchKernelGGL(k_offscl,    dim3(16),   dim3(256), 0, stream, act, w_off, b_off, w_scl, b_scl, offscl);
  hipLaunchKernelGGL(k_bias_pre,  dim3(48),   dim3(256), 0, stream, rpb, bias_g);
  hipLaunchKernelGGL(k_qkv_mfma,  dim3(16*196), dim3(256), 0, stream, x, w_qkv, b_qkv, qbuf, kbuf, vbuf);
  hipLaunchKernelGGL(k_attn_mfma, dim3(3*2048), dim3(128), 0, stream,
                     qbuf, kbuf, vbuf, offscl, bias_g, (float*)d_out);
  hipLaunchKernelGGL(k_proj_mfma, dim3(16*196), dim3(256), 0, stream,
                     (const float*)d_out, w_proj, b_proj, (float*)d_out);
}